// Round 10
// baseline (1550.003 us; speedup 1.0000x reference)
//
#include <hip/hip_runtime.h>

#define FIN 256
#define KNN 50
#define CAP 192
#define J1  512
#define MAXJC 3208

static __device__ __forceinline__ float lrelu02(float v){ return v > 0.f ? v : 0.2f*v; }
static __device__ __forceinline__ unsigned fkey(float v){
  unsigned u = __float_as_uint(v);
  return (u & 0x80000000u) ? ~u : (u | 0x80000000u);
}

// ---------------- CSR construction ----------------
__global__ __launch_bounds__(256) void k_zero_int(int* p, int n){
  int i = blockIdx.x*256 + threadIdx.x; if (i<n) p[i]=0;
}
__global__ __launch_bounds__(256) void k_count_deg(const int* __restrict__ dstv, int* deg, int E){
  int i = blockIdx.x*256 + threadIdx.x; if (i<E) atomicAdd(&deg[dstv[i]], 1);
}
__global__ __launch_bounds__(256) void k_scan(const int* __restrict__ deg, int* offs, int* cursor, int n){
  __shared__ int buf[256]; __shared__ int carry;
  int t = threadIdx.x;
  if (t==0) carry = 0;
  __syncthreads();
  for (int base=0; base<n; base+=256){
    int v = (base+t<n)? deg[base+t] : 0;
    buf[t]=v; __syncthreads();
    for (int off=1; off<256; off<<=1){
      int add = (t>=off)? buf[t-off] : 0;
      __syncthreads();
      buf[t]+=add; __syncthreads();
    }
    int excl = buf[t]-v+carry;
    if (base+t<n){ offs[base+t]=excl; cursor[base+t]=excl; }
    __syncthreads();
    if (t==0) carry += buf[255];
    __syncthreads();
  }
}
__global__ __launch_bounds__(256) void k_fill_csr(const int* __restrict__ dstv, int* cursor, int* csr, int E){
  int i = blockIdx.x*256 + threadIdx.x;
  if (i<E){ int p=atomicAdd(&cursor[dstv[i]],1); csr[p]=i; }
}
__global__ __launch_bounds__(64) void k_sort_csr_wave(int* csr, const int* __restrict__ offs, const int* __restrict__ deg, int n){
  int node = blockIdx.x; if (node>=n) return;
  int t = threadIdx.x;
  int st = offs[node], d = deg[node];
  __shared__ int buf[256];
  if (d > 256){
    if (t==0){
      for (int a=1;a<d;++a){ int v=csr[st+a]; int b=a-1;
        while (b>=0 && csr[st+b]>v){ csr[st+b+1]=csr[st+b]; --b; }
        csr[st+b+1]=v; }
    }
    return;
  }
  for (int q=t;q<d;q+=64) buf[q]=csr[st+q];
  __syncthreads();
  for (int it=0; it<d; ++it){
    int ph = it & 1;
    for (int pidx=t; 2*pidx+ph+1 < d; pidx+=64){
      int a = 2*pidx+ph;
      int va=buf[a], vb=buf[a+1];
      if (va > vb){ buf[a]=vb; buf[a+1]=va; }
    }
    __syncthreads();
  }
  for (int q=t;q<d;q+=64) csr[st+q]=buf[q];
}

// ---------------- fold attention vectors into weights ----------------
__global__ __launch_bounds__(256) void k_fold(
  const float* __restrict__ W, const float* __restrict__ as8, const float* __restrict__ ad8,
  float* __restrict__ Wf)
{
  int o = blockIdx.x;
  int t = threadIdx.x;
  int h = o & 7;
  const float* av = (o<8) ? (as8 + h*128) : (ad8 + h*128);
  const float* wp = W + (size_t)h*128*256 + t;
  float acc = 0.f;
  #pragma unroll 4
  for (int c=0;c<128;++c) acc += av[c] * wp[(size_t)c*256];
  Wf[o*256+t] = acc;
}

// ---------------- generic fp32 GEMM (64x64 tile), z-batched ----------------
__global__ __launch_bounds__(256) void gemm_bt(
    const float* __restrict__ A, int lda,
    const float* __restrict__ W, int ldw,
    const float* __restrict__ bias,
    float* __restrict__ C, int ldc, int coff,
    int M, int Kdim, int O, int relu,
    int az, int wz, int cz, int bz)
{
  A += (size_t)blockIdx.z * az;
  W += (size_t)blockIdx.z * wz;
  if (bias) bias += (size_t)blockIdx.z * bz;
  coff += blockIdx.z * cz;
  __shared__ float As[32][68];
  __shared__ float Ws[32][68];
  int t  = threadIdx.x;
  int n0 = blockIdx.y * 64;
  int o0 = blockIdx.x * 64;
  int tx = t & 15, ty = t >> 4;
  float acc[4][4] = {};
  int kgrp = t & 7;
  int row  = t >> 3;
  for (int k0 = 0; k0 < Kdim; k0 += 32) {
    #pragma unroll
    for (int p = 0; p < 2; ++p) {
      int r = row + 32*p;
      int n = n0 + r;
      float4 v = make_float4(0.f,0.f,0.f,0.f);
      if (n < M) v = *(const float4*)(A + (size_t)n*lda + k0 + 4*kgrp);
      As[4*kgrp+0][r] = v.x; As[4*kgrp+1][r] = v.y;
      As[4*kgrp+2][r] = v.z; As[4*kgrp+3][r] = v.w;
      int o = o0 + r;
      float4 w = make_float4(0.f,0.f,0.f,0.f);
      if (o < O) w = *(const float4*)(W + (size_t)o*ldw + k0 + 4*kgrp);
      Ws[4*kgrp+0][r] = w.x; Ws[4*kgrp+1][r] = w.y;
      Ws[4*kgrp+2][r] = w.z; Ws[4*kgrp+3][r] = w.w;
    }
    __syncthreads();
    #pragma unroll 8
    for (int kk = 0; kk < 32; ++kk) {
      float4 a = *(const float4*)&As[kk][ty*4];
      float4 w = *(const float4*)&Ws[kk][tx*4];
      float av[4] = {a.x,a.y,a.z,a.w};
      float wv[4] = {w.x,w.y,w.z,w.w};
      #pragma unroll
      for (int i=0;i<4;++i)
        #pragma unroll
        for (int j=0;j<4;++j) acc[i][j] += av[i]*wv[j];
    }
    __syncthreads();
  }
  #pragma unroll
  for (int i=0;i<4;++i) {
    int n = n0 + ty*4 + i;
    if (n >= M) continue;
    #pragma unroll
    for (int j=0;j<4;++j) {
      int o = o0 + tx*4 + j;
      if (o >= O) continue;
      float v = acc[i][j] + (bias ? bias[o] : 0.f);
      if (relu) v = fmaxf(v, 0.f);
      C[(size_t)n*ldc + coff + o] = v;
    }
  }
}

// ---------------- 128x128-tile GEMM, O fixed = 128, z-batched, bias optional ----
__global__ __launch_bounds__(256) void gemm128(
    const float* __restrict__ A, int lda,
    const float* __restrict__ W, int ldw,
    const float* __restrict__ bias,
    float* __restrict__ C, int ldc, int coff,
    int M, int Kdim, int relu,
    int az, int wz, int cz, int bz)
{
  A += (size_t)blockIdx.z * az;
  W += (size_t)blockIdx.z * wz;
  const float* bp = bias ? (bias + (size_t)blockIdx.z * bz) : nullptr;
  int ccol = coff + blockIdx.z * cz;
  __shared__ float As[32][132];
  __shared__ float Ws[32][132];
  int t = threadIdx.x;
  int n0 = blockIdx.y * 128;
  int kg = t & 7, rb = t >> 3;
  int tx = t & 15, ty = t >> 4;
  float acc[2][2][4][4] = {};
  for (int k0 = 0; k0 < Kdim; k0 += 32) {
    __syncthreads();
    #pragma unroll
    for (int p = 0; p < 4; ++p) {
      int r = rb + 32*p;
      int n = n0 + r;
      float4 v = make_float4(0.f,0.f,0.f,0.f);
      if (n < M) v = *(const float4*)(A + (size_t)n*lda + k0 + 4*kg);
      As[4*kg+0][r]=v.x; As[4*kg+1][r]=v.y; As[4*kg+2][r]=v.z; As[4*kg+3][r]=v.w;
      float4 w = *(const float4*)(W + (size_t)r*ldw + k0 + 4*kg);
      Ws[4*kg+0][r]=w.x; Ws[4*kg+1][r]=w.y; Ws[4*kg+2][r]=w.z; Ws[4*kg+3][r]=w.w;
    }
    __syncthreads();
    #pragma unroll 8
    for (int kk = 0; kk < 32; ++kk) {
      float4 A0 = *(const float4*)&As[kk][ty*4];
      float4 A1 = *(const float4*)&As[kk][64+ty*4];
      float4 B0 = *(const float4*)&Ws[kk][tx*4];
      float4 B1 = *(const float4*)&Ws[kk][64+tx*4];
      float av[2][4] = {{A0.x,A0.y,A0.z,A0.w},{A1.x,A1.y,A1.z,A1.w}};
      float bv[2][4] = {{B0.x,B0.y,B0.z,B0.w},{B1.x,B1.y,B1.z,B1.w}};
      #pragma unroll
      for (int pi=0;pi<2;++pi)
        #pragma unroll
        for (int pj=0;pj<2;++pj)
          #pragma unroll
          for (int i=0;i<4;++i)
            #pragma unroll
            for (int j=0;j<4;++j)
              acc[pi][pj][i][j] += av[pi][i]*bv[pj][j];
    }
  }
  #pragma unroll
  for (int pi=0;pi<2;++pi)
    #pragma unroll
    for (int i=0;i<4;++i) {
      int n = n0 + pi*64 + ty*4 + i;
      if (n >= M) continue;
      #pragma unroll
      for (int pj=0;pj<2;++pj)
        #pragma unroll
        for (int j=0;j<4;++j) {
          int o = pj*64 + tx*4 + j;
          float v = acc[pi][pj][i][j] + (bp ? bp[o] : 0.f);
          if (relu) v = fmaxf(v, 0.f);
          C[(size_t)n*ldc + ccol + o] = v;
        }
    }
}

// ---------------- attention logits (gat2, H=1) ----------------
__global__ __launch_bounds__(256) void att_logits(
    const float* __restrict__ hbuf, const float* __restrict__ asrc,
    const float* __restrict__ adst, float* __restrict__ als, float* __restrict__ ald,
    int H, int M)
{
  int gidx = blockIdx.x*256 + threadIdx.x;
  if (gidx >= M*H) return;
  int n = gidx / H, h = gidx % H;
  const float* hp = hbuf + (size_t)n*H*128 + (size_t)h*128;
  const float* as = asrc + h*128;
  const float* ad = adst + h*128;
  float s1=0.f, s2=0.f;
  for (int c=0;c<128;++c){ float v=hp[c]; s1 += v*as[c]; s2 += v*ad[c]; }
  als[gidx]=s1; ald[gidx]=s2;
}

// ---------------- gat1: input-space softmax aggregation ----------------
template<int NH>
__global__ __launch_bounds__(256) void gat1_agg_x(
    const float* __restrict__ x, const float* __restrict__ al1,
    const int* __restrict__ csr, const int* __restrict__ offs, const int* __restrict__ deg,
    const int* __restrict__ srcv,
    float* __restrict__ agg, int h0, int M)
{
  const int n = blockIdx.x, t = threadIdx.x;
  const int d = deg[n], st = offs[n];
  const int lane = t & 63, w = t >> 6;
  __shared__ float sh_ald[NH];
  __shared__ float wpart[4*NH];
  __shared__ float emax_s[NH], den_s[NH];
  __shared__ int   s_lds[128];
  __shared__ float alpha_lds[128*NH];
  if (t < NH) sh_ald[t] = al1[(size_t)n*16 + 8 + h0 + t];
  __syncthreads();
  float lm[NH];
  #pragma unroll
  for (int h=0;h<NH;++h) lm[h] = -__builtin_inff();
  for (int q=t; q<d; q+=256) {
    int s = srcv[csr[st+q]];
    float av[NH];
    float4 a0 = *(const float4*)(al1 + (size_t)s*16 + h0);
    av[0]=a0.x; av[1]=a0.y; av[2]=a0.z; av[3]=a0.w;
    if constexpr (NH==8){
      float4 a1 = *(const float4*)(al1 + (size_t)s*16 + h0 + 4);
      av[4]=a1.x; av[5]=a1.y; av[6]=a1.z; av[7]=a1.w;
    }
    #pragma unroll
    for (int h=0;h<NH;++h) lm[h] = fmaxf(lm[h], lrelu02(av[h] + sh_ald[h]));
  }
  #pragma unroll
  for (int h=0;h<NH;++h){
    float v = lm[h];
    for (int off=32;off>0;off>>=1) v = fmaxf(v, __shfl_down(v, off, 64));
    if (lane==0) wpart[w*NH+h] = v;
  }
  __syncthreads();
  if (t < NH)
    emax_s[t] = fmaxf(fmaxf(wpart[t], wpart[NH+t]), fmaxf(wpart[2*NH+t], wpart[3*NH+t]));
  __syncthreads();
  float ls[NH];
  #pragma unroll
  for (int h=0;h<NH;++h) ls[h]=0.f;
  for (int q=t; q<d; q+=256) {
    int s = srcv[csr[st+q]];
    float av[NH];
    float4 a0 = *(const float4*)(al1 + (size_t)s*16 + h0);
    av[0]=a0.x; av[1]=a0.y; av[2]=a0.z; av[3]=a0.w;
    if constexpr (NH==8){
      float4 a1 = *(const float4*)(al1 + (size_t)s*16 + h0 + 4);
      av[4]=a1.x; av[5]=a1.y; av[6]=a1.z; av[7]=a1.w;
    }
    #pragma unroll
    for (int h=0;h<NH;++h) ls[h] += expf(lrelu02(av[h] + sh_ald[h]) - emax_s[h]);
  }
  #pragma unroll
  for (int h=0;h<NH;++h){
    float v = ls[h];
    for (int off=32;off>0;off>>=1) v += __shfl_down(v, off, 64);
    if (lane==0) wpart[w*NH+h] = v;
  }
  __syncthreads();
  if (t < NH)
    den_s[t] = wpart[t] + wpart[NH+t] + wpart[2*NH+t] + wpart[3*NH+t] + 1e-16f;
  float acc[NH];
  #pragma unroll
  for (int h=0;h<NH;++h) acc[h]=0.f;
  for (int c0=0; c0<d; c0+=128) {
    int cl = min(128, d-c0);
    __syncthreads();
    for (int q=t; q<cl; q+=256) s_lds[q] = srcv[csr[st+c0+q]];
    __syncthreads();
    for (int idx=t; idx<cl*NH; idx+=256) {
      int q = idx / NH, h = idx % NH;
      float als = al1[(size_t)s_lds[q]*16 + h0 + h];
      float v = lrelu02(als + sh_ald[h]);
      alpha_lds[q*NH+h] = expf(v - emax_s[h]) / den_s[h];
    }
    __syncthreads();
    for (int q=0; q<cl; ++q) {
      float xv = x[(size_t)s_lds[q]*FIN + t];
      #pragma unroll
      for (int h=0;h<NH;++h) acc[h] += alpha_lds[q*NH+h] * xv;
    }
  }
  #pragma unroll
  for (int h=0;h<NH;++h) agg[(size_t)n*(NH*256) + h*256 + t] = acc[h];
}

// ---------------- gat2 aggregation: one wave per node ----------------
__global__ __launch_bounds__(256) void gat2_agg_wave(
  const float* __restrict__ h2, const float* __restrict__ als, const float* __restrict__ ald,
  const int* __restrict__ csr, const int* __restrict__ offs, const int* __restrict__ deg,
  const int* __restrict__ srcv, const float* __restrict__ bias,
  float* __restrict__ cat, int M)
{
  int wid = blockIdx.x*4 + (threadIdx.x>>6);
  int lane = threadIdx.x & 63;
  if (wid >= M) return;
  int d = deg[wid], st = offs[wid];
  float aldn = ald[wid];
  float lm = -__builtin_inff();
  for (int q=lane;q<d;q+=64){ int s=srcv[csr[st+q]]; lm = fmaxf(lm, lrelu02(als[s]+aldn)); }
  #pragma unroll
  for (int m=1;m<64;m<<=1) lm = fmaxf(lm, __shfl_xor(lm, m, 64));
  float ls = 0.f;
  for (int q=lane;q<d;q+=64){ int s=srcv[csr[st+q]]; ls += expf(lrelu02(als[s]+aldn)-lm); }
  #pragma unroll
  for (int m=1;m<64;m<<=1) ls += __shfl_xor(ls, m, 64);
  float den = ls + 1e-16f;
  float a0=0.f, a1=0.f;
  for (int q=0;q<d;++q){
    int s = srcv[csr[st+q]];
    float alpha = expf(lrelu02(als[s]+aldn)-lm)/den;
    float2 hv = *(const float2*)(h2 + (size_t)s*128 + lane*2);
    a0 += alpha*hv.x; a1 += alpha*hv.y;
  }
  a0 += bias[lane*2]; a1 += bias[lane*2+1];
  *(float2*)(cat + (size_t)wid*512 + 128 + lane*2) = make_float2(a0,a1);
}

// ---------------- knn: sq norms / init ----------------
__global__ __launch_bounds__(256) void k_sq(const float* __restrict__ g, float* sq, int n){
  int i = blockIdx.x*256+threadIdx.x;
  if (i<n){ const float* p=g+(size_t)i*64; float s=0.f; for(int c=0;c<64;++c) s+=p[c]*p[c]; sq[i]=s; }
}
__global__ __launch_bounds__(256) void k_init_topk(unsigned int* tk, int* ti, int n){
  int i = blockIdx.x*256+threadIdx.x;
  if (i<n){ tk[i]=0u; ti[i]=0x7fffffff; }
}

// ---------------- gram v5: 64(i) x 256(j) tile, 4x16 micro, swizzled LDS -------
// Per k: 1 A-read + 4 B-reads per 64 FMAs -> LDS pipe undersubscribed.
// MODE 0: store slab (row stride J1). MODE 1: filter only, no slab store.
template<int MODE>
__global__ __launch_bounds__(256) void gram256(
    const float* __restrict__ G, const float* __restrict__ sqv,
    const unsigned* __restrict__ kth,
    float* __restrict__ slab, int* __restrict__ cnt,
    unsigned* __restrict__ ck, int* __restrict__ ci,
    int j0, int jcount, int M)
{
  __shared__ float4 GiS[32*16];   // 8 KB : 32 k x 16 slots (64 i)
  __shared__ float4 GjS[32*64];   // 32 KB: 32 k x 64 slots (256 j)
  float* Gif = (float*)GiS;
  float* Gjf = (float*)GjS;
  int t = threadIdx.x;
  int i0  = blockIdx.y * 64;
  int jt0 = blockIdx.x * 256;
  int tx = t & 15, ty = t >> 4;
  int kg = t & 7, rw = t >> 3;
  float acc[4][4][4] = {};        // [jb][i][j]
  #pragma unroll
  for (int h=0; h<2; ++h) {
    if (h) __syncthreads();
    #pragma unroll
    for (int rr=0; rr<2; ++rr) {
      int r = rw + 32*rr;
      int slotA = (r>>2) ^ kg;
      int gi = i0 + r;
      float4 v = (gi<M) ? *(const float4*)(G + (size_t)gi*64 + h*32 + 4*kg) : make_float4(0,0,0,0);
      Gif[((4*kg+0)*16 + slotA)*4 + (r&3)] = v.x;
      Gif[((4*kg+1)*16 + slotA)*4 + (r&3)] = v.y;
      Gif[((4*kg+2)*16 + slotA)*4 + (r&3)] = v.z;
      Gif[((4*kg+3)*16 + slotA)*4 + (r&3)] = v.w;
    }
    #pragma unroll
    for (int rr=0; rr<8; ++rr) {
      int r = rw + 32*rr;
      int slotB = (r>>2) ^ kg;
      int gj = j0 + jt0 + r;
      float4 w = (gj<M) ? *(const float4*)(G + (size_t)gj*64 + h*32 + 4*kg) : make_float4(0,0,0,0);
      Gjf[((4*kg+0)*64 + slotB)*4 + (r&3)] = w.x;
      Gjf[((4*kg+1)*64 + slotB)*4 + (r&3)] = w.y;
      Gjf[((4*kg+2)*64 + slotB)*4 + (r&3)] = w.z;
      Gjf[((4*kg+3)*64 + slotB)*4 + (r&3)] = w.w;
    }
    __syncthreads();
    #pragma unroll 8
    for (int k=0; k<32; ++k) {
      int kc3 = (k>>2)&7;
      float4 A0 = GiS[k*16 + (ty ^ kc3)];
      float av[4] = {A0.x,A0.y,A0.z,A0.w};
      #pragma unroll
      for (int jb=0;jb<4;++jb){
        float4 B = GjS[k*64 + ((tx + 16*jb) ^ kc3)];
        float bv[4] = {B.x,B.y,B.z,B.w};
        #pragma unroll
        for (int i=0;i<4;++i)
          #pragma unroll
          for (int j=0;j<4;++j)
            acc[jb][i][j] += av[i]*bv[j];
      }
    }
  }
  #pragma unroll
  for (int i=0;i<4;++i){
    int ii = i0 + ty*4 + i;
    if (ii >= M) continue;
    float sqi = sqv[ii];
    #pragma unroll
    for (int jb=0;jb<4;++jb){
      int jl0 = jt0 + jb*64 + tx*4;
      if (jl0 >= jcount) continue;        // jcount%4==0 -> whole float4 in or out
      float4 v4;
      v4.x = 2.f*acc[jb][i][0] - sqi - sqv[j0+jl0+0];
      v4.y = 2.f*acc[jb][i][1] - sqi - sqv[j0+jl0+1];
      v4.z = 2.f*acc[jb][i][2] - sqi - sqv[j0+jl0+2];
      v4.w = 2.f*acc[jb][i][3] - sqi - sqv[j0+jl0+3];
      if (MODE == 0) {
        *(float4*)(slab + (size_t)ii*J1 + jl0) = v4;
      } else {
        unsigned kt = kth[ii];
        float vv[4] = {v4.x, v4.y, v4.z, v4.w};
        #pragma unroll
        for (int j=0;j<4;++j){
          unsigned key = fkey(vv[j]);
          if (key > kt){
            int pos = atomicAdd(&cnt[ii], 1);
            if (pos < CAP){ ck[(size_t)ii*CAP+pos] = key; ci[(size_t)ii*CAP+pos] = j0+jl0+j; }
          }
        }
      }
    }
  }
}

// ---------------- slab-1 top-50: radix select (J1 cols, 4-wave private hist) ---
__global__ __launch_bounds__(256) void topk_radix(
    const float* __restrict__ slab, int j0, int jcount,
    unsigned* __restrict__ tkk, int* __restrict__ tki, unsigned* __restrict__ kth, int M)
{
  __shared__ unsigned keys[J1 + KNN];
  __shared__ int hist[4*256];
  __shared__ int red2[256];
  __shared__ int oldidx[KNN];
  __shared__ int outidx[KNN];
  __shared__ unsigned outkey[KNN];
  __shared__ int b_star, cnt2;
  int i = blockIdx.x, t = threadIdx.x, w = t >> 6;
  for (int p=t; p<jcount; p+=256) keys[p] = fkey(slab[(size_t)i*J1 + p]);
  if (t < KNN){ keys[jcount+t] = tkk[(size_t)i*KNN+t]; oldidx[t] = tki[(size_t)i*KNN+t]; }
  if (t == 0) cnt2 = 0;
  __syncthreads();
  const int total = jcount + KNN;
  unsigned prefix = 0, pmask = 0;
  int need = KNN;
  #pragma unroll
  for (int pass=0; pass<4; ++pass) {
    int shift = 24 - 8*pass;
    hist[t]=0; hist[256+t]=0; hist[512+t]=0; hist[768+t]=0;
    __syncthreads();
    for (int p=t; p<total; p+=256) {
      unsigned k = keys[p];
      if ((k & pmask) == prefix) atomicAdd(&hist[(w<<8) + ((k>>shift)&255)], 1);
    }
    __syncthreads();
    red2[t] = hist[t] + hist[256+t] + hist[512+t] + hist[768+t];
    __syncthreads();
    for (int off=1; off<256; off<<=1) {
      int v = (t+off<256) ? red2[t+off] : 0;
      __syncthreads();
      red2[t] += v;
      __syncthreads();
    }
    if (red2[t] >= need && (t==255 || red2[t+1] < need)) b_star = t;
    __syncthreads();
    int b = b_star;
    need -= (b < 255) ? red2[b+1] : 0;
    prefix |= ((unsigned)b) << shift;
    pmask  |= 0xFFu << shift;
    __syncthreads();
  }
  for (int p=t; p<total; p+=256) {
    unsigned k = keys[p];
    if (k > prefix) {
      int pos = atomicAdd(&cnt2, 1);
      outidx[pos] = (p < jcount) ? (j0 + p) : oldidx[p-jcount];
      outkey[pos] = k;
    }
  }
  __syncthreads();
  int base = cnt2;
  int last = -1;
  for (int it=0; it<need; ++it) {
    int best = 0x7fffffff;
    for (int p=t; p<total; p+=256) {
      if (keys[p] == prefix) {
        int idx = (p < jcount) ? (j0 + p) : oldidx[p-jcount];
        if (idx > last && idx < best) best = idx;
      }
    }
    red2[t] = best; __syncthreads();
    for (int s=128;s>0;s>>=1){ if (t<s) red2[t] = min(red2[t], red2[t+s]); __syncthreads(); }
    if (t==0) { outidx[base+it] = red2[0]; outkey[base+it] = prefix; }
    last = red2[0];
    __syncthreads();
  }
  if (t < KNN){ tkk[(size_t)i*KNN+t] = outkey[t]; tki[(size_t)i*KNN+t] = outidx[t]; }
  if (t == 0) kth[i] = prefix;
}

// ---------------- filter slabs: bitonic fast path; overflow -> recompute+radix --
__global__ __launch_bounds__(256) void topk_fast(
    const float* __restrict__ G, const float* __restrict__ sqv,
    int j0, int jcount,
    const unsigned* __restrict__ ck, const int* __restrict__ ci, const int* __restrict__ cnt,
    unsigned* __restrict__ tkk, int* __restrict__ tki, unsigned* __restrict__ kth, int M)
{
  int i = blockIdx.x, t = threadIdx.x;
  int c = cnt[i];
  if (c <= CAP) {
    __shared__ unsigned skey[256];
    __shared__ int sidx[256];
    unsigned k = 0u; int id = 0x7fffffff;
    if (t < KNN){ k = tkk[(size_t)i*KNN+t]; id = tki[(size_t)i*KNN+t]; }
    else if (t-KNN < c){ k = ck[(size_t)i*CAP + (t-KNN)]; id = ci[(size_t)i*CAP + (t-KNN)]; }
    skey[t] = k; sidx[t] = id;
    for (int size=2; size<=256; size<<=1){
      for (int stride=size>>1; stride>0; stride>>=1){
        __syncthreads();
        int p = t ^ stride;
        if (p > t){
          unsigned k1=skey[t], k2=skey[p]; int i1=sidx[t], i2=sidx[p];
          bool b21 = (k2>k1) || (k2==k1 && i2<i1);
          bool b12 = (k1>k2) || (k1==k2 && i1<i2);
          bool desc = ((t & size) == 0);
          if (desc ? b21 : b12){
            skey[t]=k2; skey[p]=k1; sidx[t]=i2; sidx[p]=i1;
          }
        }
      }
    }
    __syncthreads();
    if (t < KNN){ tkk[(size_t)i*KNN+t] = skey[t]; tki[(size_t)i*KNN+t] = sidx[t]; }
    if (t == 0) kth[i] = skey[KNN-1];
  } else {
    // overflow: recompute row distances (same FMA order as gram) then radix
    __shared__ float gvec[64];
    __shared__ unsigned keys[MAXJC + KNN];
    __shared__ int hist[256];
    __shared__ int red2[256];
    __shared__ int oldidx[KNN];
    __shared__ int outidx[KNN];
    __shared__ unsigned outkey[KNN];
    __shared__ int b_star, cnt2;
    if (t < 64) gvec[t] = G[(size_t)i*64 + t];
    if (t == 0) cnt2 = 0;
    __syncthreads();
    float sqi = sqv[i];
    for (int p=t; p<jcount; p+=256){
      const float4* gj4 = (const float4*)(G + (size_t)(j0+p)*64);
      float acc = 0.f;
      #pragma unroll 4
      for (int q=0;q<16;++q){
        float4 w = gj4[q];
        acc += gvec[4*q+0]*w.x;
        acc += gvec[4*q+1]*w.y;
        acc += gvec[4*q+2]*w.z;
        acc += gvec[4*q+3]*w.w;
      }
      keys[p] = fkey(2.f*acc - sqi - sqv[j0+p]);
    }
    if (t < KNN){ keys[jcount+t] = tkk[(size_t)i*KNN+t]; oldidx[t] = tki[(size_t)i*KNN+t]; }
    __syncthreads();
    const int total = jcount + KNN;
    unsigned prefix = 0, pmask = 0;
    int need = KNN;
    #pragma unroll
    for (int pass=0; pass<4; ++pass) {
      int shift = 24 - 8*pass;
      hist[t] = 0; __syncthreads();
      for (int p=t; p<total; p+=256) {
        unsigned k = keys[p];
        if ((k & pmask) == prefix) atomicAdd(&hist[(k>>shift)&255], 1);
      }
      __syncthreads();
      for (int off=1; off<256; off<<=1) {
        int v = (t+off<256) ? hist[t+off] : 0;
        __syncthreads();
        hist[t] += v;
        __syncthreads();
      }
      if (hist[t] >= need && (t==255 || hist[t+1] < need)) b_star = t;
      __syncthreads();
      int b = b_star;
      need -= (b < 255) ? hist[b+1] : 0;
      prefix |= ((unsigned)b) << shift;
      pmask  |= 0xFFu << shift;
      __syncthreads();
    }
    for (int p=t; p<total; p+=256) {
      unsigned k = keys[p];
      if (k > prefix) {
        int pos = atomicAdd(&cnt2, 1);
        outidx[pos] = (p < jcount) ? (j0 + p) : oldidx[p-jcount];
        outkey[pos] = k;
      }
    }
    __syncthreads();
    int base = cnt2;
    int last = -1;
    for (int it=0; it<need; ++it) {
      int best = 0x7fffffff;
      for (int p=t; p<total; p+=256) {
        if (keys[p] == prefix) {
          int idx = (p < jcount) ? (j0 + p) : oldidx[p-jcount];
          if (idx > last && idx < best) best = idx;
        }
      }
      red2[t] = best; __syncthreads();
      for (int s=128;s>0;s>>=1){ if (t<s) red2[t] = min(red2[t], red2[t+s]); __syncthreads(); }
      if (t==0) { outidx[base+it] = red2[0]; outkey[base+it] = prefix; }
      last = red2[0];
      __syncthreads();
    }
    if (t < KNN){ tkk[(size_t)i*KNN+t] = outkey[t]; tki[(size_t)i*KNN+t] = outidx[t]; }
    if (t == 0) kth[i] = prefix;
  }
}

// ---------------- gather-mean over top-50 + LayerNorm ----------------
__global__ __launch_bounds__(256) void knn_mean_ln(
    float* __restrict__ cat, const int* __restrict__ topi,
    const float* __restrict__ g, const float* __restrict__ b, int M)
{
  int i = blockIdx.x; int t = threadIdx.x;
  __shared__ int idx[KNN];
  __shared__ float red[256];
  if (t<KNN) idx[t]=topi[(size_t)i*KNN+t];
  __syncthreads();
  float acc=0.f;
  for (int r=0;r<KNN;++r) acc += cat[(size_t)idx[r]*512 + t];
  float xval = acc * (1.f/KNN);
  red[t]=xval; __syncthreads();
  for (int s=128;s>0;s>>=1){ if(t<s) red[t]+=red[t+s]; __syncthreads(); }
  float mu = red[0]*(1.f/256.f); __syncthreads();
  float d = xval-mu;
  red[t]=d*d; __syncthreads();
  for (int s=128;s>0;s>>=1){ if(t<s) red[t]+=red[t+s]; __syncthreads(); }
  float var = red[0]*(1.f/256.f);
  float y = d * rsqrtf(var+1e-5f) * g[t] + b[t];
  cat[(size_t)i*512 + 256 + t] = y;
}

// ================================================================
extern "C" void kernel_launch(void* const* d_in, const int* in_sizes, int n_in,
                              void* d_out, int out_size, void* d_ws, size_t ws_size,
                              hipStream_t stream)
{
  const float* x      = (const float*)d_in[0];
  const int*   ei     = (const int*)  d_in[1];
  const float* lin1_w = (const float*)d_in[2];
  const float* lin1_b = (const float*)d_in[3];
  const float* gat1_w = (const float*)d_in[4];
  const float* g1_as  = (const float*)d_in[5];
  const float* g1_ad  = (const float*)d_in[6];
  const float* gat1_b = (const float*)d_in[7];
  const float* gat2_w = (const float*)d_in[8];
  const float* g2_as  = (const float*)d_in[9];
  const float* g2_ad  = (const float*)d_in[10];
  const float* gat2_b = (const float*)d_in[11];
  const float* proj_w = (const float*)d_in[12];
  const float* proj_b = (const float*)d_in[13];
  const float* ln_g   = (const float*)d_in[14];
  const float* ln_b   = (const float*)d_in[15];
  const float* lin_w  = (const float*)d_in[16];
  const float* lin_b  = (const float*)d_in[17];
  float* outp = (float*)d_out;

  const int N = in_sizes[0]/FIN;    // 10000
  const int E = in_sizes[1]/2;      // 320000
  const int* srcv = ei;
  const int* dstv = ei + E;

  size_t needFull = sizeof(float)*((size_t)N*(2048+1024+512+16+128+1+1+64+1+KNN+KNN+1+1+1+1+1+2*CAP) + E + 4096);
  bool full = ws_size >= needFull;
  size_t aggF = full ? (size_t)N*2048 : (size_t)N*1024;

  float* ws = (float*)d_ws;
  size_t f = 0;
  float* agg  = ws + f; f += aggF;
  float* xg   = ws + f; f += (size_t)N*1024;
  float* slab = agg;                      // overlays agg (row stride J1); dead by knn time
  float* cat  = ws + f; f += (size_t)N*512;
  float* al1  = ws + f; f += (size_t)N*16;
  float* h2   = ws + f; f += (size_t)N*128;
  float* al2s = ws + f; f += (size_t)N;
  float* al2d = ws + f; f += (size_t)N;
  float* gsc  = ws + f; f += (size_t)N*64;
  float* sqv  = ws + f; f += (size_t)N;
  unsigned* tkk = (unsigned*)(ws + f); f += (size_t)N*KNN;
  int* tki    = (int*)(ws + f); f += (size_t)N*KNN;
  int* deg    = (int*)(ws + f); f += (size_t)N;
  int* offs   = (int*)(ws + f); f += (size_t)N;
  int* cursor = (int*)(ws + f); f += (size_t)N;
  unsigned* kth = (unsigned*)(ws + f); f += (size_t)N;
  int* ccnt   = (int*)(ws + f); f += (size_t)N;
  unsigned* ck = (unsigned*)(ws + f); f += (size_t)N*CAP;
  int* ci     = (int*)(ws + f); f += (size_t)N*CAP;
  int* csr    = (int*)(ws + f); f += (size_t)E;
  float* Wf   = ws + f; f += 4096;
  (void)n_in; (void)out_size;

  dim3 b256(256);
  int gy = (N+63)/64;
  int gy128 = (N+127)/128;
  int gy64 = (N+63)/64;

  // CSR by dst
  k_zero_int<<<(N+255)/256, b256, 0, stream>>>(deg, N);
  k_count_deg<<<(E+255)/256, b256, 0, stream>>>(dstv, deg, E);
  k_scan<<<1, b256, 0, stream>>>(deg, offs, cursor, N);
  k_fill_csr<<<(E+255)/256, b256, 0, stream>>>(dstv, cursor, csr, E);
  k_sort_csr_wave<<<N, dim3(64), 0, stream>>>(csr, offs, deg, N);

  // fold att vectors into weights; al1 = x @ Wf^T  ([N,16])
  k_fold<<<16, b256, 0, stream>>>(gat1_w, g1_as, g1_ad, Wf);
  gemm_bt<<<dim3(1,gy,1), b256, 0, stream>>>(x,FIN, Wf,FIN, nullptr, al1,16,0, N,FIN,16, 0, 0,0,0,0);

  // x1 = relu(x@lin1_w.T + b) -> cat[:, :128]  (O=128 -> gemm128)
  gemm128<<<dim3(1,gy128,1), b256, 0, stream>>>(x,FIN, lin1_w,FIN, lin1_b, cat,512,0, N,FIN, 1, 0,0,0,0);

  // gat1: input-space aggregation, then per-head 128-tile GEMM -> xg = relu(. + b)
  if (full) {
    gat1_agg_x<8><<<N, b256, 0, stream>>>(x, al1, csr, offs, deg, srcv, agg, 0, N);
    gemm128<<<dim3(1,gy128,8), b256, 0, stream>>>(agg,2048, gat1_w,FIN, gat1_b, xg,1024,0,
                                                  N,FIN, 1, 256, 128*256, 128, 128);
  } else {
    for (int h0=0; h0<8; h0+=4) {
      gat1_agg_x<4><<<N, b256, 0, stream>>>(x, al1, csr, offs, deg, srcv, agg, h0, N);
      gemm128<<<dim3(1,gy128,4), b256, 0, stream>>>(agg,1024, gat1_w + (size_t)h0*128*256,FIN,
                                                    gat1_b + h0*128, xg,1024, h0*128,
                                                    N,FIN, 1, 256, 128*256, 128, 128);
    }
  }

  // gat2 (H=1): h2 = xg @ gat2_w.T (O=128 -> gemm128, no bias); logits; wave agg
  gemm128<<<dim3(1,gy128,1), b256, 0, stream>>>(xg,1024, gat2_w,1024, nullptr, h2,128,0, N,1024, 0, 0,0,0,0);
  att_logits<<<(N+255)/256, b256, 0, stream>>>(h2, g2_as, g2_ad, al2s, al2d, 1, N);
  gat2_agg_wave<<<(N+3)/4, b256, 0, stream>>>(h2, al2s, al2d, csr, offs, deg, srcv, gat2_b, cat, N);

  // g_score = final @ proj_w.T + proj_b
  gemm_bt<<<dim3(1,gy,1), b256, 0, stream>>>(cat,512, proj_w,256, proj_b, gsc,64,0, N,256,64, 0, 0,0,0,0);
  k_sq<<<(N+255)/256, b256, 0, stream>>>(gsc, sqv, N);
  k_init_topk<<<(N*KNN+255)/256, b256, 0, stream>>>(tkk, tki, N*KNN);
  k_zero_int<<<(N+255)/256, b256, 0, stream>>>((int*)kth, N);

  // knn with geometric slabs: slab 1 (512 cols) = materialize + radix;
  // slabs 2-5 = threshold filter + bitonic (overflow -> recompute+radix)
  const int sj0[5] = {0, 512, 1536, 3584, 6792};
  const int sjc[5] = {512, 1024, 2048, 3208, 3208};
  for (int s = 0; s < 5; ++s){
    int j0 = sj0[s], jc = sjc[s];
    if (jc > N - j0) jc = N - j0;
    if (jc <= 0) break;
    if (s == 0) {
      gram256<0><<<dim3((jc+255)/256, gy64), b256, 0, stream>>>(gsc, sqv, kth, slab, ccnt, ck, ci, j0, jc, N);
      topk_radix<<<N, b256, 0, stream>>>(slab, j0, jc, tkk, tki, kth, N);
    } else {
      k_zero_int<<<(N+255)/256, b256, 0, stream>>>(ccnt, N);
      gram256<1><<<dim3((jc+255)/256, gy64), b256, 0, stream>>>(gsc, sqv, kth, slab, ccnt, ck, ci, j0, jc, N);
      topk_fast<<<N, b256, 0, stream>>>(gsc, sqv, j0, jc, ck, ci, ccnt, tkk, tki, kth, N);
    }
  }
  knn_mean_ln<<<N, b256, 0, stream>>>(cat, tki, ln_g, ln_b, N);
  // out = [final, sim] @ lin_w.T + lin_b
  gemm_bt<<<dim3(1,gy,1), b256, 0, stream>>>(cat,512, lin_w,512, lin_b, outp,64,0, N,512,64, 0, 0,0,0,0);
}

// Round 11
// 1292.172 us; speedup vs baseline: 1.1995x; 1.1995x over previous
//
#include <hip/hip_runtime.h>

#define FIN 256
#define KNN 50
#define CAP 192
#define J1  512
#define MAXJC 3208

static __device__ __forceinline__ float lrelu02(float v){ return v > 0.f ? v : 0.2f*v; }
static __device__ __forceinline__ unsigned fkey(float v){
  unsigned u = __float_as_uint(v);
  return (u & 0x80000000u) ? ~u : (u | 0x80000000u);
}

// ---------------- CSR construction ----------------
__global__ __launch_bounds__(256) void k_zero_int(int* p, int n){
  int i = blockIdx.x*256 + threadIdx.x; if (i<n) p[i]=0;
}
__global__ __launch_bounds__(256) void k_count_deg(const int* __restrict__ dstv, int* deg, int E){
  int i = blockIdx.x*256 + threadIdx.x; if (i<E) atomicAdd(&deg[dstv[i]], 1);
}
__global__ __launch_bounds__(256) void k_scan(const int* __restrict__ deg, int* offs, int* cursor, int n){
  __shared__ int buf[256]; __shared__ int carry;
  int t = threadIdx.x;
  if (t==0) carry = 0;
  __syncthreads();
  for (int base=0; base<n; base+=256){
    int v = (base+t<n)? deg[base+t] : 0;
    buf[t]=v; __syncthreads();
    for (int off=1; off<256; off<<=1){
      int add = (t>=off)? buf[t-off] : 0;
      __syncthreads();
      buf[t]+=add; __syncthreads();
    }
    int excl = buf[t]-v+carry;
    if (base+t<n){ offs[base+t]=excl; cursor[base+t]=excl; }
    __syncthreads();
    if (t==0) carry += buf[255];
    __syncthreads();
  }
}
__global__ __launch_bounds__(256) void k_fill_csr(const int* __restrict__ dstv, int* cursor, int* csr, int E){
  int i = blockIdx.x*256 + threadIdx.x;
  if (i<E){ int p=atomicAdd(&cursor[dstv[i]],1); csr[p]=i; }
}
__global__ __launch_bounds__(64) void k_sort_csr_wave(int* csr, const int* __restrict__ offs, const int* __restrict__ deg, int n){
  int node = blockIdx.x; if (node>=n) return;
  int t = threadIdx.x;
  int st = offs[node], d = deg[node];
  __shared__ int buf[256];
  if (d > 256){
    if (t==0){
      for (int a=1;a<d;++a){ int v=csr[st+a]; int b=a-1;
        while (b>=0 && csr[st+b]>v){ csr[st+b+1]=csr[st+b]; --b; }
        csr[st+b+1]=v; }
    }
    return;
  }
  for (int q=t;q<d;q+=64) buf[q]=csr[st+q];
  __syncthreads();
  for (int it=0; it<d; ++it){
    int ph = it & 1;
    for (int pidx=t; 2*pidx+ph+1 < d; pidx+=64){
      int a = 2*pidx+ph;
      int va=buf[a], vb=buf[a+1];
      if (va > vb){ buf[a]=vb; buf[a+1]=va; }
    }
    __syncthreads();
  }
  for (int q=t;q<d;q+=64) csr[st+q]=buf[q];
}

// ---------------- fold attention vectors into weights ----------------
__global__ __launch_bounds__(256) void k_fold(
  const float* __restrict__ W, const float* __restrict__ as8, const float* __restrict__ ad8,
  float* __restrict__ Wf)
{
  int o = blockIdx.x;
  int t = threadIdx.x;
  int h = o & 7;
  const float* av = (o<8) ? (as8 + h*128) : (ad8 + h*128);
  const float* wp = W + (size_t)h*128*256 + t;
  float acc = 0.f;
  #pragma unroll 4
  for (int c=0;c<128;++c) acc += av[c] * wp[(size_t)c*256];
  Wf[o*256+t] = acc;
}

// ---------------- generic fp32 GEMM (64x64 tile), z-batched ----------------
__global__ __launch_bounds__(256) void gemm_bt(
    const float* __restrict__ A, int lda,
    const float* __restrict__ W, int ldw,
    const float* __restrict__ bias,
    float* __restrict__ C, int ldc, int coff,
    int M, int Kdim, int O, int relu,
    int az, int wz, int cz, int bz)
{
  A += (size_t)blockIdx.z * az;
  W += (size_t)blockIdx.z * wz;
  if (bias) bias += (size_t)blockIdx.z * bz;
  coff += blockIdx.z * cz;
  __shared__ float As[32][68];
  __shared__ float Ws[32][68];
  int t  = threadIdx.x;
  int n0 = blockIdx.y * 64;
  int o0 = blockIdx.x * 64;
  int tx = t & 15, ty = t >> 4;
  float acc[4][4] = {};
  int kgrp = t & 7;
  int row  = t >> 3;
  for (int k0 = 0; k0 < Kdim; k0 += 32) {
    #pragma unroll
    for (int p = 0; p < 2; ++p) {
      int r = row + 32*p;
      int n = n0 + r;
      float4 v = make_float4(0.f,0.f,0.f,0.f);
      if (n < M) v = *(const float4*)(A + (size_t)n*lda + k0 + 4*kgrp);
      As[4*kgrp+0][r] = v.x; As[4*kgrp+1][r] = v.y;
      As[4*kgrp+2][r] = v.z; As[4*kgrp+3][r] = v.w;
      int o = o0 + r;
      float4 w = make_float4(0.f,0.f,0.f,0.f);
      if (o < O) w = *(const float4*)(W + (size_t)o*ldw + k0 + 4*kgrp);
      Ws[4*kgrp+0][r] = w.x; Ws[4*kgrp+1][r] = w.y;
      Ws[4*kgrp+2][r] = w.z; Ws[4*kgrp+3][r] = w.w;
    }
    __syncthreads();
    #pragma unroll 8
    for (int kk = 0; kk < 32; ++kk) {
      float4 a = *(const float4*)&As[kk][ty*4];
      float4 w = *(const float4*)&Ws[kk][tx*4];
      float av[4] = {a.x,a.y,a.z,a.w};
      float wv[4] = {w.x,w.y,w.z,w.w};
      #pragma unroll
      for (int i=0;i<4;++i)
        #pragma unroll
        for (int j=0;j<4;++j) acc[i][j] += av[i]*wv[j];
    }
    __syncthreads();
  }
  #pragma unroll
  for (int i=0;i<4;++i) {
    int n = n0 + ty*4 + i;
    if (n >= M) continue;
    #pragma unroll
    for (int j=0;j<4;++j) {
      int o = o0 + tx*4 + j;
      if (o >= O) continue;
      float v = acc[i][j] + (bias ? bias[o] : 0.f);
      if (relu) v = fmaxf(v, 0.f);
      C[(size_t)n*ldc + coff + o] = v;
    }
  }
}

// ---------------- 128x128-tile GEMM, O fixed = 128, z-batched ----------------
__global__ __launch_bounds__(256) void gemm128(
    const float* __restrict__ A, int lda,
    const float* __restrict__ W, int ldw,
    const float* __restrict__ bias,
    float* __restrict__ C, int ldc, int coff,
    int M, int Kdim, int relu,
    int az, int wz, int cz, int bz)
{
  A += (size_t)blockIdx.z * az;
  W += (size_t)blockIdx.z * wz;
  const float* bp = bias + (size_t)blockIdx.z * bz;
  int ccol = coff + blockIdx.z * cz;
  __shared__ float As[32][132];
  __shared__ float Ws[32][132];
  int t = threadIdx.x;
  int n0 = blockIdx.y * 128;
  int kg = t & 7, rb = t >> 3;
  int tx = t & 15, ty = t >> 4;
  float acc[2][2][4][4] = {};
  for (int k0 = 0; k0 < Kdim; k0 += 32) {
    __syncthreads();
    #pragma unroll
    for (int p = 0; p < 4; ++p) {
      int r = rb + 32*p;
      int n = n0 + r;
      float4 v = make_float4(0.f,0.f,0.f,0.f);
      if (n < M) v = *(const float4*)(A + (size_t)n*lda + k0 + 4*kg);
      As[4*kg+0][r]=v.x; As[4*kg+1][r]=v.y; As[4*kg+2][r]=v.z; As[4*kg+3][r]=v.w;
      float4 w = *(const float4*)(W + (size_t)r*ldw + k0 + 4*kg);
      Ws[4*kg+0][r]=w.x; Ws[4*kg+1][r]=w.y; Ws[4*kg+2][r]=w.z; Ws[4*kg+3][r]=w.w;
    }
    __syncthreads();
    #pragma unroll 8
    for (int kk = 0; kk < 32; ++kk) {
      float4 A0 = *(const float4*)&As[kk][ty*4];
      float4 A1 = *(const float4*)&As[kk][64+ty*4];
      float4 B0 = *(const float4*)&Ws[kk][tx*4];
      float4 B1 = *(const float4*)&Ws[kk][64+tx*4];
      float av[2][4] = {{A0.x,A0.y,A0.z,A0.w},{A1.x,A1.y,A1.z,A1.w}};
      float bv[2][4] = {{B0.x,B0.y,B0.z,B0.w},{B1.x,B1.y,B1.z,B1.w}};
      #pragma unroll
      for (int pi=0;pi<2;++pi)
        #pragma unroll
        for (int pj=0;pj<2;++pj)
          #pragma unroll
          for (int i=0;i<4;++i)
            #pragma unroll
            for (int j=0;j<4;++j)
              acc[pi][pj][i][j] += av[pi][i]*bv[pj][j];
    }
  }
  #pragma unroll
  for (int pi=0;pi<2;++pi)
    #pragma unroll
    for (int i=0;i<4;++i) {
      int n = n0 + pi*64 + ty*4 + i;
      if (n >= M) continue;
      #pragma unroll
      for (int pj=0;pj<2;++pj)
        #pragma unroll
        for (int j=0;j<4;++j) {
          int o = pj*64 + tx*4 + j;
          float v = acc[pi][pj][i][j] + bp[o];
          if (relu) v = fmaxf(v, 0.f);
          C[(size_t)n*ldc + ccol + o] = v;
        }
    }
}

// ---------------- dedicated h2 GEMM: C[Mx128] = A[Mx1024] @ W[128x1024]^T ------
// gram-style 64(i) x 128(o) tile, k-major XOR-swizzled float4 LDS, 32 acc/thread.
__global__ __launch_bounds__(256) void gemm_h2(
    const float* __restrict__ A, const float* __restrict__ W,
    float* __restrict__ C, int M)
{
  __shared__ float4 AiS[32*16];   // 8 KB : 32 k x 16 slots (64 rows)
  __shared__ float4 WjS[32*32];   // 16 KB: 32 k x 32 slots (128 rows)
  float* Aif = (float*)AiS;
  float* Wjf = (float*)WjS;
  int t = threadIdx.x;
  int i0 = blockIdx.x * 64;
  int tx = t & 15, ty = t >> 4;
  int kg = t & 7, rw = t >> 3;
  float acc[2][4][4] = {};        // [oj][i][j]
  for (int h=0; h<32; ++h) {      // 32 chunks of k=32 (K=1024)
    if (h) __syncthreads();
    #pragma unroll
    for (int rr=0; rr<2; ++rr) {
      int r = rw + 32*rr;
      int slotA = (r>>2) ^ kg;
      int gi = i0 + r;
      float4 v = (gi<M) ? *(const float4*)(A + (size_t)gi*1024 + h*32 + 4*kg) : make_float4(0,0,0,0);
      Aif[((4*kg+0)*16 + slotA)*4 + (r&3)] = v.x;
      Aif[((4*kg+1)*16 + slotA)*4 + (r&3)] = v.y;
      Aif[((4*kg+2)*16 + slotA)*4 + (r&3)] = v.z;
      Aif[((4*kg+3)*16 + slotA)*4 + (r&3)] = v.w;
    }
    #pragma unroll
    for (int rr=0; rr<4; ++rr) {
      int r = rw + 32*rr;
      int slotB = (r>>2) ^ kg;
      float4 w = *(const float4*)(W + (size_t)r*1024 + h*32 + 4*kg);
      Wjf[((4*kg+0)*32 + slotB)*4 + (r&3)] = w.x;
      Wjf[((4*kg+1)*32 + slotB)*4 + (r&3)] = w.y;
      Wjf[((4*kg+2)*32 + slotB)*4 + (r&3)] = w.z;
      Wjf[((4*kg+3)*32 + slotB)*4 + (r&3)] = w.w;
    }
    __syncthreads();
    #pragma unroll 8
    for (int k=0; k<32; ++k) {
      int kc3 = (k>>2)&7;
      float4 A0 = AiS[k*16 + (ty ^ kc3)];
      float4 B0 = WjS[k*32 + (tx ^ kc3)];
      float4 B1 = WjS[k*32 + 16 + (tx ^ kc3)];
      float av[4] = {A0.x,A0.y,A0.z,A0.w};
      float bv[2][4] = {{B0.x,B0.y,B0.z,B0.w},{B1.x,B1.y,B1.z,B1.w}};
      #pragma unroll
      for (int oj=0;oj<2;++oj)
        #pragma unroll
        for (int i=0;i<4;++i)
          #pragma unroll
          for (int j=0;j<4;++j)
            acc[oj][i][j] += av[i]*bv[oj][j];
    }
  }
  #pragma unroll
  for (int i=0;i<4;++i){
    int n = i0 + ty*4 + i;
    if (n >= M) continue;
    #pragma unroll
    for (int oj=0;oj<2;++oj){
      float4 v4 = make_float4(acc[oj][i][0], acc[oj][i][1], acc[oj][i][2], acc[oj][i][3]);
      *(float4*)(C + (size_t)n*128 + oj*64 + tx*4) = v4;
    }
  }
}

// ---------------- attention logits (gat2, H=1) ----------------
__global__ __launch_bounds__(256) void att_logits(
    const float* __restrict__ hbuf, const float* __restrict__ asrc,
    const float* __restrict__ adst, float* __restrict__ als, float* __restrict__ ald,
    int H, int M)
{
  int gidx = blockIdx.x*256 + threadIdx.x;
  if (gidx >= M*H) return;
  int n = gidx / H, h = gidx % H;
  const float* hp = hbuf + (size_t)n*H*128 + (size_t)h*128;
  const float* as = asrc + h*128;
  const float* ad = adst + h*128;
  float s1=0.f, s2=0.f;
  for (int c=0;c<128;++c){ float v=hp[c]; s1 += v*as[c]; s2 += v*ad[c]; }
  als[gidx]=s1; ald[gidx]=s2;
}

// ---------------- gat1: input-space softmax aggregation ----------------
template<int NH>
__global__ __launch_bounds__(256) void gat1_agg_x(
    const float* __restrict__ x, const float* __restrict__ al1,
    const int* __restrict__ csr, const int* __restrict__ offs, const int* __restrict__ deg,
    const int* __restrict__ srcv,
    float* __restrict__ agg, int h0, int M)
{
  const int n = blockIdx.x, t = threadIdx.x;
  const int d = deg[n], st = offs[n];
  const int lane = t & 63, w = t >> 6;
  __shared__ float sh_ald[NH];
  __shared__ float wpart[4*NH];
  __shared__ float emax_s[NH], den_s[NH];
  __shared__ int   s_lds[128];
  __shared__ float alpha_lds[128*NH];
  if (t < NH) sh_ald[t] = al1[(size_t)n*16 + 8 + h0 + t];
  __syncthreads();
  float lm[NH];
  #pragma unroll
  for (int h=0;h<NH;++h) lm[h] = -__builtin_inff();
  for (int q=t; q<d; q+=256) {
    int s = srcv[csr[st+q]];
    float av[NH];
    float4 a0 = *(const float4*)(al1 + (size_t)s*16 + h0);
    av[0]=a0.x; av[1]=a0.y; av[2]=a0.z; av[3]=a0.w;
    if constexpr (NH==8){
      float4 a1 = *(const float4*)(al1 + (size_t)s*16 + h0 + 4);
      av[4]=a1.x; av[5]=a1.y; av[6]=a1.z; av[7]=a1.w;
    }
    #pragma unroll
    for (int h=0;h<NH;++h) lm[h] = fmaxf(lm[h], lrelu02(av[h] + sh_ald[h]));
  }
  #pragma unroll
  for (int h=0;h<NH;++h){
    float v = lm[h];
    for (int off=32;off>0;off>>=1) v = fmaxf(v, __shfl_down(v, off, 64));
    if (lane==0) wpart[w*NH+h] = v;
  }
  __syncthreads();
  if (t < NH)
    emax_s[t] = fmaxf(fmaxf(wpart[t], wpart[NH+t]), fmaxf(wpart[2*NH+t], wpart[3*NH+t]));
  __syncthreads();
  float ls[NH];
  #pragma unroll
  for (int h=0;h<NH;++h) ls[h]=0.f;
  for (int q=t; q<d; q+=256) {
    int s = srcv[csr[st+q]];
    float av[NH];
    float4 a0 = *(const float4*)(al1 + (size_t)s*16 + h0);
    av[0]=a0.x; av[1]=a0.y; av[2]=a0.z; av[3]=a0.w;
    if constexpr (NH==8){
      float4 a1 = *(const float4*)(al1 + (size_t)s*16 + h0 + 4);
      av[4]=a1.x; av[5]=a1.y; av[6]=a1.z; av[7]=a1.w;
    }
    #pragma unroll
    for (int h=0;h<NH;++h) ls[h] += expf(lrelu02(av[h] + sh_ald[h]) - emax_s[h]);
  }
  #pragma unroll
  for (int h=0;h<NH;++h){
    float v = ls[h];
    for (int off=32;off>0;off>>=1) v += __shfl_down(v, off, 64);
    if (lane==0) wpart[w*NH+h] = v;
  }
  __syncthreads();
  if (t < NH)
    den_s[t] = wpart[t] + wpart[NH+t] + wpart[2*NH+t] + wpart[3*NH+t] + 1e-16f;
  float acc[NH];
  #pragma unroll
  for (int h=0;h<NH;++h) acc[h]=0.f;
  for (int c0=0; c0<d; c0+=128) {
    int cl = min(128, d-c0);
    __syncthreads();
    for (int q=t; q<cl; q+=256) s_lds[q] = srcv[csr[st+c0+q]];
    __syncthreads();
    for (int idx=t; idx<cl*NH; idx+=256) {
      int q = idx / NH, h = idx % NH;
      float als = al1[(size_t)s_lds[q]*16 + h0 + h];
      float v = lrelu02(als + sh_ald[h]);
      alpha_lds[q*NH+h] = expf(v - emax_s[h]) / den_s[h];
    }
    __syncthreads();
    for (int q=0; q<cl; ++q) {
      float xv = x[(size_t)s_lds[q]*FIN + t];
      #pragma unroll
      for (int h=0;h<NH;++h) acc[h] += alpha_lds[q*NH+h] * xv;
    }
  }
  #pragma unroll
  for (int h=0;h<NH;++h) agg[(size_t)n*(NH*256) + h*256 + t] = acc[h];
}

// ---------------- gat2 aggregation: one wave per node ----------------
__global__ __launch_bounds__(256) void gat2_agg_wave(
  const float* __restrict__ h2, const float* __restrict__ als, const float* __restrict__ ald,
  const int* __restrict__ csr, const int* __restrict__ offs, const int* __restrict__ deg,
  const int* __restrict__ srcv, const float* __restrict__ bias,
  float* __restrict__ cat, int M)
{
  int wid = blockIdx.x*4 + (threadIdx.x>>6);
  int lane = threadIdx.x & 63;
  if (wid >= M) return;
  int d = deg[wid], st = offs[wid];
  float aldn = ald[wid];
  float lm = -__builtin_inff();
  for (int q=lane;q<d;q+=64){ int s=srcv[csr[st+q]]; lm = fmaxf(lm, lrelu02(als[s]+aldn)); }
  #pragma unroll
  for (int m=1;m<64;m<<=1) lm = fmaxf(lm, __shfl_xor(lm, m, 64));
  float ls = 0.f;
  for (int q=lane;q<d;q+=64){ int s=srcv[csr[st+q]]; ls += expf(lrelu02(als[s]+aldn)-lm); }
  #pragma unroll
  for (int m=1;m<64;m<<=1) ls += __shfl_xor(ls, m, 64);
  float den = ls + 1e-16f;
  float a0=0.f, a1=0.f;
  for (int q=0;q<d;++q){
    int s = srcv[csr[st+q]];
    float alpha = expf(lrelu02(als[s]+aldn)-lm)/den;
    float2 hv = *(const float2*)(h2 + (size_t)s*128 + lane*2);
    a0 += alpha*hv.x; a1 += alpha*hv.y;
  }
  a0 += bias[lane*2]; a1 += bias[lane*2+1];
  *(float2*)(cat + (size_t)wid*512 + 128 + lane*2) = make_float2(a0,a1);
}

// ---------------- knn: sq norms / init ----------------
__global__ __launch_bounds__(256) void k_sq(const float* __restrict__ g, float* sq, int n){
  int i = blockIdx.x*256+threadIdx.x;
  if (i<n){ const float* p=g+(size_t)i*64; float s=0.f; for(int c=0;c<64;++c) s+=p[c]*p[c]; sq[i]=s; }
}
__global__ __launch_bounds__(256) void k_init_topk(unsigned int* tk, int* ti, int n){
  int i = blockIdx.x*256+threadIdx.x;
  if (i<n){ tk[i]=0u; ti[i]=0x7fffffff; }
}

// ---------------- gram: 64(i) x 128(j) tile, 32 acc, swizzled LDS --------------
// Compile-time slab width JC (static guards -> stable codegen, no spill).
// MODE 0: store slab (row stride J1). MODE 1: threshold filter only.
template<int MODE, int JC>
__global__ __launch_bounds__(256) void gram_k(
    const float* __restrict__ G, const float* __restrict__ sqv,
    const unsigned* __restrict__ kth,
    float* __restrict__ slab, int* __restrict__ cnt,
    unsigned* __restrict__ ck, int* __restrict__ ci,
    int j0, int M)
{
  __shared__ float4 GiS[32*16];
  __shared__ float4 GjS[32*32];
  float* Gif = (float*)GiS;
  float* Gjf = (float*)GjS;
  int t = threadIdx.x;
  int i0  = blockIdx.y * 64;
  int jt0 = blockIdx.x * 128;
  int tx = t & 15, ty = t >> 4;
  int kg = t & 7, rw = t >> 3;
  float acc[2][4][4] = {};
  #pragma unroll
  for (int h=0; h<2; ++h) {
    if (h) __syncthreads();
    #pragma unroll
    for (int rr=0; rr<2; ++rr) {
      int r = rw + 32*rr;
      int slotA = (r>>2) ^ kg;
      int gi = i0 + r;
      float4 v = (gi<M) ? *(const float4*)(G + (size_t)gi*64 + h*32 + 4*kg) : make_float4(0,0,0,0);
      Gif[((4*kg+0)*16 + slotA)*4 + (r&3)] = v.x;
      Gif[((4*kg+1)*16 + slotA)*4 + (r&3)] = v.y;
      Gif[((4*kg+2)*16 + slotA)*4 + (r&3)] = v.z;
      Gif[((4*kg+3)*16 + slotA)*4 + (r&3)] = v.w;
    }
    #pragma unroll
    for (int rr=0; rr<4; ++rr) {
      int r = rw + 32*rr;
      int slotB = (r>>2) ^ kg;
      int gj = j0 + jt0 + r;
      float4 w = (gj<M) ? *(const float4*)(G + (size_t)gj*64 + h*32 + 4*kg) : make_float4(0,0,0,0);
      Gjf[((4*kg+0)*32 + slotB)*4 + (r&3)] = w.x;
      Gjf[((4*kg+1)*32 + slotB)*4 + (r&3)] = w.y;
      Gjf[((4*kg+2)*32 + slotB)*4 + (r&3)] = w.z;
      Gjf[((4*kg+3)*32 + slotB)*4 + (r&3)] = w.w;
    }
    __syncthreads();
    #pragma unroll 8
    for (int k=0; k<32; ++k) {
      int kc3 = (k>>2)&7;
      float4 A0 = GiS[k*16 + (ty ^ kc3)];
      float4 B0 = GjS[k*32 + (tx ^ kc3)];
      float4 B1 = GjS[k*32 + 16 + (tx ^ kc3)];
      float av[4] = {A0.x,A0.y,A0.z,A0.w};
      float bv[2][4] = {{B0.x,B0.y,B0.z,B0.w},{B1.x,B1.y,B1.z,B1.w}};
      #pragma unroll
      for (int pj=0;pj<2;++pj)
        #pragma unroll
        for (int i=0;i<4;++i)
          #pragma unroll
          for (int j=0;j<4;++j)
            acc[pj][i][j] += av[i]*bv[pj][j];
    }
  }
  #pragma unroll
  for (int i=0;i<4;++i){
    int ii = i0 + ty*4 + i;
    if (ii >= M) continue;
    float sqi = sqv[ii];
    #pragma unroll
    for (int pj=0;pj<2;++pj){
      int jl0 = jt0 + pj*64 + tx*4;
      if (jl0 >= JC) continue;            // compile-time slab width
      float4 v4;
      v4.x = 2.f*acc[pj][i][0] - sqi - sqv[j0+jl0+0];
      v4.y = 2.f*acc[pj][i][1] - sqi - sqv[j0+jl0+1];
      v4.z = 2.f*acc[pj][i][2] - sqi - sqv[j0+jl0+2];
      v4.w = 2.f*acc[pj][i][3] - sqi - sqv[j0+jl0+3];
      if (MODE == 0) {
        *(float4*)(slab + (size_t)ii*J1 + jl0) = v4;
      } else {
        unsigned kt = kth[ii];
        float vv[4] = {v4.x, v4.y, v4.z, v4.w};
        #pragma unroll
        for (int j=0;j<4;++j){
          unsigned key = fkey(vv[j]);
          if (key > kt){
            int pos = atomicAdd(&cnt[ii], 1);
            if (pos < CAP){ ck[(size_t)ii*CAP+pos] = key; ci[(size_t)ii*CAP+pos] = j0+jl0+j; }
          }
        }
      }
    }
  }
}

// ---------------- slab-1 top-50: radix select (J1 cols, 4-wave private hist) ---
__global__ __launch_bounds__(256) void topk_radix(
    const float* __restrict__ slab, int j0, int jcount,
    unsigned* __restrict__ tkk, int* __restrict__ tki, unsigned* __restrict__ kth, int M)
{
  __shared__ unsigned keys[J1 + KNN];
  __shared__ int hist[4*256];
  __shared__ int red2[256];
  __shared__ int oldidx[KNN];
  __shared__ int outidx[KNN];
  __shared__ unsigned outkey[KNN];
  __shared__ int b_star, cnt2;
  int i = blockIdx.x, t = threadIdx.x, w = t >> 6;
  for (int p=t; p<jcount; p+=256) keys[p] = fkey(slab[(size_t)i*J1 + p]);
  if (t < KNN){ keys[jcount+t] = tkk[(size_t)i*KNN+t]; oldidx[t] = tki[(size_t)i*KNN+t]; }
  if (t == 0) cnt2 = 0;
  __syncthreads();
  const int total = jcount + KNN;
  unsigned prefix = 0, pmask = 0;
  int need = KNN;
  #pragma unroll
  for (int pass=0; pass<4; ++pass) {
    int shift = 24 - 8*pass;
    hist[t]=0; hist[256+t]=0; hist[512+t]=0; hist[768+t]=0;
    __syncthreads();
    for (int p=t; p<total; p+=256) {
      unsigned k = keys[p];
      if ((k & pmask) == prefix) atomicAdd(&hist[(w<<8) + ((k>>shift)&255)], 1);
    }
    __syncthreads();
    red2[t] = hist[t] + hist[256+t] + hist[512+t] + hist[768+t];
    __syncthreads();
    for (int off=1; off<256; off<<=1) {
      int v = (t+off<256) ? red2[t+off] : 0;
      __syncthreads();
      red2[t] += v;
      __syncthreads();
    }
    if (red2[t] >= need && (t==255 || red2[t+1] < need)) b_star = t;
    __syncthreads();
    int b = b_star;
    need -= (b < 255) ? red2[b+1] : 0;
    prefix |= ((unsigned)b) << shift;
    pmask  |= 0xFFu << shift;
    __syncthreads();
  }
  for (int p=t; p<total; p+=256) {
    unsigned k = keys[p];
    if (k > prefix) {
      int pos = atomicAdd(&cnt2, 1);
      outidx[pos] = (p < jcount) ? (j0 + p) : oldidx[p-jcount];
      outkey[pos] = k;
    }
  }
  __syncthreads();
  int base = cnt2;
  int last = -1;
  for (int it=0; it<need; ++it) {
    int best = 0x7fffffff;
    for (int p=t; p<total; p+=256) {
      if (keys[p] == prefix) {
        int idx = (p < jcount) ? (j0 + p) : oldidx[p-jcount];
        if (idx > last && idx < best) best = idx;
      }
    }
    red2[t] = best; __syncthreads();
    for (int s=128;s>0;s>>=1){ if (t<s) red2[t] = min(red2[t], red2[t+s]); __syncthreads(); }
    if (t==0) { outidx[base+it] = red2[0]; outkey[base+it] = prefix; }
    last = red2[0];
    __syncthreads();
  }
  if (t < KNN){ tkk[(size_t)i*KNN+t] = outkey[t]; tki[(size_t)i*KNN+t] = outidx[t]; }
  if (t == 0) kth[i] = prefix;
}

// ---------------- filter slabs: bitonic fast path; overflow -> recompute+radix --
__global__ __launch_bounds__(256) void topk_fast(
    const float* __restrict__ G, const float* __restrict__ sqv,
    int j0, int jcount,
    const unsigned* __restrict__ ck, const int* __restrict__ ci, const int* __restrict__ cnt,
    unsigned* __restrict__ tkk, int* __restrict__ tki, unsigned* __restrict__ kth, int M)
{
  int i = blockIdx.x, t = threadIdx.x;
  int c = cnt[i];
  if (c <= CAP) {
    __shared__ unsigned skey[256];
    __shared__ int sidx[256];
    unsigned k = 0u; int id = 0x7fffffff;
    if (t < KNN){ k = tkk[(size_t)i*KNN+t]; id = tki[(size_t)i*KNN+t]; }
    else if (t-KNN < c){ k = ck[(size_t)i*CAP + (t-KNN)]; id = ci[(size_t)i*CAP + (t-KNN)]; }
    skey[t] = k; sidx[t] = id;
    for (int size=2; size<=256; size<<=1){
      for (int stride=size>>1; stride>0; stride>>=1){
        __syncthreads();
        int p = t ^ stride;
        if (p > t){
          unsigned k1=skey[t], k2=skey[p]; int i1=sidx[t], i2=sidx[p];
          bool b21 = (k2>k1) || (k2==k1 && i2<i1);
          bool b12 = (k1>k2) || (k1==k2 && i1<i2);
          bool desc = ((t & size) == 0);
          if (desc ? b21 : b12){
            skey[t]=k2; skey[p]=k1; sidx[t]=i2; sidx[p]=i1;
          }
        }
      }
    }
    __syncthreads();
    if (t < KNN){ tkk[(size_t)i*KNN+t] = skey[t]; tki[(size_t)i*KNN+t] = sidx[t]; }
    if (t == 0) kth[i] = skey[KNN-1];
  } else {
    // overflow: recompute row distances (same FMA order as gram) then radix
    __shared__ float gvec[64];
    __shared__ unsigned keys[MAXJC + KNN];
    __shared__ int hist[256];
    __shared__ int red2[256];
    __shared__ int oldidx[KNN];
    __shared__ int outidx[KNN];
    __shared__ unsigned outkey[KNN];
    __shared__ int b_star, cnt2;
    if (t < 64) gvec[t] = G[(size_t)i*64 + t];
    if (t == 0) cnt2 = 0;
    __syncthreads();
    float sqi = sqv[i];
    for (int p=t; p<jcount; p+=256){
      const float4* gj4 = (const float4*)(G + (size_t)(j0+p)*64);
      float acc = 0.f;
      #pragma unroll 4
      for (int q=0;q<16;++q){
        float4 w = gj4[q];
        acc += gvec[4*q+0]*w.x;
        acc += gvec[4*q+1]*w.y;
        acc += gvec[4*q+2]*w.z;
        acc += gvec[4*q+3]*w.w;
      }
      keys[p] = fkey(2.f*acc - sqi - sqv[j0+p]);
    }
    if (t < KNN){ keys[jcount+t] = tkk[(size_t)i*KNN+t]; oldidx[t] = tki[(size_t)i*KNN+t]; }
    __syncthreads();
    const int total = jcount + KNN;
    unsigned prefix = 0, pmask = 0;
    int need = KNN;
    #pragma unroll
    for (int pass=0; pass<4; ++pass) {
      int shift = 24 - 8*pass;
      hist[t] = 0; __syncthreads();
      for (int p=t; p<total; p+=256) {
        unsigned k = keys[p];
        if ((k & pmask) == prefix) atomicAdd(&hist[(k>>shift)&255], 1);
      }
      __syncthreads();
      for (int off=1; off<256; off<<=1) {
        int v = (t+off<256) ? hist[t+off] : 0;
        __syncthreads();
        hist[t] += v;
        __syncthreads();
      }
      if (hist[t] >= need && (t==255 || hist[t+1] < need)) b_star = t;
      __syncthreads();
      int b = b_star;
      need -= (b < 255) ? hist[b+1] : 0;
      prefix |= ((unsigned)b) << shift;
      pmask  |= 0xFFu << shift;
      __syncthreads();
    }
    for (int p=t; p<total; p+=256) {
      unsigned k = keys[p];
      if (k > prefix) {
        int pos = atomicAdd(&cnt2, 1);
        outidx[pos] = (p < jcount) ? (j0 + p) : oldidx[p-jcount];
        outkey[pos] = k;
      }
    }
    __syncthreads();
    int base = cnt2;
    int last = -1;
    for (int it=0; it<need; ++it) {
      int best = 0x7fffffff;
      for (int p=t; p<total; p+=256) {
        if (keys[p] == prefix) {
          int idx = (p < jcount) ? (j0 + p) : oldidx[p-jcount];
          if (idx > last && idx < best) best = idx;
        }
      }
      red2[t] = best; __syncthreads();
      for (int s=128;s>0;s>>=1){ if (t<s) red2[t] = min(red2[t], red2[t+s]); __syncthreads(); }
      if (t==0) { outidx[base+it] = red2[0]; outkey[base+it] = prefix; }
      last = red2[0];
      __syncthreads();
    }
    if (t < KNN){ tkk[(size_t)i*KNN+t] = outkey[t]; tki[(size_t)i*KNN+t] = outidx[t]; }
    if (t == 0) kth[i] = prefix;
  }
}

// ---------------- gather-mean over top-50 + LayerNorm ----------------
__global__ __launch_bounds__(256) void knn_mean_ln(
    float* __restrict__ cat, const int* __restrict__ topi,
    const float* __restrict__ g, const float* __restrict__ b, int M)
{
  int i = blockIdx.x; int t = threadIdx.x;
  __shared__ int idx[KNN];
  __shared__ float red[256];
  if (t<KNN) idx[t]=topi[(size_t)i*KNN+t];
  __syncthreads();
  float acc=0.f;
  for (int r=0;r<KNN;++r) acc += cat[(size_t)idx[r]*512 + t];
  float xval = acc * (1.f/KNN);
  red[t]=xval; __syncthreads();
  for (int s=128;s>0;s>>=1){ if(t<s) red[t]+=red[t+s]; __syncthreads(); }
  float mu = red[0]*(1.f/256.f); __syncthreads();
  float d = xval-mu;
  red[t]=d*d; __syncthreads();
  for (int s=128;s>0;s>>=1){ if(t<s) red[t]+=red[t+s]; __syncthreads(); }
  float var = red[0]*(1.f/256.f);
  float y = d * rsqrtf(var+1e-5f) * g[t] + b[t];
  cat[(size_t)i*512 + 256 + t] = y;
}

// ================================================================
extern "C" void kernel_launch(void* const* d_in, const int* in_sizes, int n_in,
                              void* d_out, int out_size, void* d_ws, size_t ws_size,
                              hipStream_t stream)
{
  const float* x      = (const float*)d_in[0];
  const int*   ei     = (const int*)  d_in[1];
  const float* lin1_w = (const float*)d_in[2];
  const float* lin1_b = (const float*)d_in[3];
  const float* gat1_w = (const float*)d_in[4];
  const float* g1_as  = (const float*)d_in[5];
  const float* g1_ad  = (const float*)d_in[6];
  const float* gat1_b = (const float*)d_in[7];
  const float* gat2_w = (const float*)d_in[8];
  const float* g2_as  = (const float*)d_in[9];
  const float* g2_ad  = (const float*)d_in[10];
  const float* gat2_b = (const float*)d_in[11];
  const float* proj_w = (const float*)d_in[12];
  const float* proj_b = (const float*)d_in[13];
  const float* ln_g   = (const float*)d_in[14];
  const float* ln_b   = (const float*)d_in[15];
  const float* lin_w  = (const float*)d_in[16];
  const float* lin_b  = (const float*)d_in[17];
  float* outp = (float*)d_out;

  const int N = in_sizes[0]/FIN;    // 10000
  const int E = in_sizes[1]/2;      // 320000
  const int* srcv = ei;
  const int* dstv = ei + E;

  size_t needFull = sizeof(float)*((size_t)N*(2048+1024+512+16+128+1+1+64+1+KNN+KNN+1+1+1+1+1+2*CAP) + E + 4096);
  bool full = ws_size >= needFull;
  size_t aggF = full ? (size_t)N*2048 : (size_t)N*1024;

  float* ws = (float*)d_ws;
  size_t f = 0;
  float* agg  = ws + f; f += aggF;
  float* xg   = ws + f; f += (size_t)N*1024;
  float* slab = agg;                      // overlays agg (row stride J1); dead by knn time
  float* cat  = ws + f; f += (size_t)N*512;
  float* al1  = ws + f; f += (size_t)N*16;
  float* h2   = ws + f; f += (size_t)N*128;
  float* al2s = ws + f; f += (size_t)N;
  float* al2d = ws + f; f += (size_t)N;
  float* gsc  = ws + f; f += (size_t)N*64;
  float* sqv  = ws + f; f += (size_t)N;
  unsigned* tkk = (unsigned*)(ws + f); f += (size_t)N*KNN;
  int* tki    = (int*)(ws + f); f += (size_t)N*KNN;
  int* deg    = (int*)(ws + f); f += (size_t)N;
  int* offs   = (int*)(ws + f); f += (size_t)N;
  int* cursor = (int*)(ws + f); f += (size_t)N;
  unsigned* kth = (unsigned*)(ws + f); f += (size_t)N;
  int* ccnt   = (int*)(ws + f); f += (size_t)N;
  unsigned* ck = (unsigned*)(ws + f); f += (size_t)N*CAP;
  int* ci     = (int*)(ws + f); f += (size_t)N*CAP;
  int* csr    = (int*)(ws + f); f += (size_t)E;
  float* Wf   = ws + f; f += 4096;
  (void)n_in; (void)out_size;

  dim3 b256(256);
  int gy = (N+63)/64;
  int gy128 = (N+127)/128;
  int gy64 = (N+63)/64;

  // CSR by dst
  k_zero_int<<<(N+255)/256, b256, 0, stream>>>(deg, N);
  k_count_deg<<<(E+255)/256, b256, 0, stream>>>(dstv, deg, E);
  k_scan<<<1, b256, 0, stream>>>(deg, offs, cursor, N);
  k_fill_csr<<<(E+255)/256, b256, 0, stream>>>(dstv, cursor, csr, E);
  k_sort_csr_wave<<<N, dim3(64), 0, stream>>>(csr, offs, deg, N);

  // fold att vectors into weights; al1 = x @ Wf^T  ([N,16])
  k_fold<<<16, b256, 0, stream>>>(gat1_w, g1_as, g1_ad, Wf);
  gemm_bt<<<dim3(1,gy,1), b256, 0, stream>>>(x,FIN, Wf,FIN, nullptr, al1,16,0, N,FIN,16, 0, 0,0,0,0);

  // x1 = relu(x@lin1_w.T + b) -> cat[:, :128]
  gemm_bt<<<dim3(2,gy,1), b256, 0, stream>>>(x,FIN, lin1_w,FIN, lin1_b, cat,512,0, N,FIN,128, 1, 0,0,0,0);

  // gat1: input-space aggregation, then per-head 128-tile GEMM -> xg = relu(. + b)
  if (full) {
    gat1_agg_x<8><<<N, b256, 0, stream>>>(x, al1, csr, offs, deg, srcv, agg, 0, N);
    gemm128<<<dim3(1,gy128,8), b256, 0, stream>>>(agg,2048, gat1_w,FIN, gat1_b, xg,1024,0,
                                                  N,FIN, 1, 256, 128*256, 128, 128);
  } else {
    for (int h0=0; h0<8; h0+=4) {
      gat1_agg_x<4><<<N, b256, 0, stream>>>(x, al1, csr, offs, deg, srcv, agg, h0, N);
      gemm128<<<dim3(1,gy128,4), b256, 0, stream>>>(agg,1024, gat1_w + (size_t)h0*128*256,FIN,
                                                    gat1_b + h0*128, xg,1024, h0*128,
                                                    N,FIN, 1, 256, 128*256, 128, 128);
    }
  }

  // gat2 (H=1): h2 = xg @ gat2_w.T (dedicated 64x128 kernel); logits; wave agg
  gemm_h2<<<gy64, b256, 0, stream>>>(xg, gat2_w, h2, N);
  att_logits<<<(N+255)/256, b256, 0, stream>>>(h2, g2_as, g2_ad, al2s, al2d, 1, N);
  gat2_agg_wave<<<(N+3)/4, b256, 0, stream>>>(h2, al2s, al2d, csr, offs, deg, srcv, gat2_b, cat, N);

  // g_score = final @ proj_w.T + proj_b
  gemm_bt<<<dim3(1,gy,1), b256, 0, stream>>>(cat,512, proj_w,256, proj_b, gsc,64,0, N,256,64, 0, 0,0,0,0);
  k_sq<<<(N+255)/256, b256, 0, stream>>>(gsc, sqv, N);
  k_init_topk<<<(N*KNN+255)/256, b256, 0, stream>>>(tkk, tki, N*KNN);
  k_zero_int<<<(N+255)/256, b256, 0, stream>>>((int*)kth, N);

  // knn with geometric slabs: slab 1 (512) = materialize + radix;
  // slabs 2-5 = threshold filter + bitonic (overflow -> recompute+radix)
  const int sj0[5] = {0, 512, 1536, 3584, 6792};
  const int sjc[5] = {512, 1024, 2048, 3208, 3208};
  for (int s = 0; s < 5; ++s){
    int j0 = sj0[s];
    int jc = sjc[s];
    if (jc > N - j0) jc = N - j0;
    if (jc <= 0) break;
    if (s == 0) {
      gram_k<0,512><<<dim3((512+127)/128, gy64), b256, 0, stream>>>(gsc, sqv, kth, slab, ccnt, ck, ci, j0, N);
      topk_radix<<<N, b256, 0, stream>>>(slab, j0, jc, tkk, tki, kth, N);
    } else {
      k_zero_int<<<(N+255)/256, b256, 0, stream>>>(ccnt, N);
      if (s == 1)
        gram_k<1,1024><<<dim3((1024+127)/128, gy64), b256, 0, stream>>>(gsc, sqv, kth, slab, ccnt, ck, ci, j0, N);
      else if (s == 2)
        gram_k<1,2048><<<dim3((2048+127)/128, gy64), b256, 0, stream>>>(gsc, sqv, kth, slab, ccnt, ck, ci, j0, N);
      else
        gram_k<1,3208><<<dim3((3208+127)/128, gy64), b256, 0, stream>>>(gsc, sqv, kth, slab, ccnt, ck, ci, j0, N);
      topk_fast<<<N, b256, 0, stream>>>(gsc, sqv, j0, jc, ck, ci, ccnt, tkk, tki, kth, N);
    }
  }
  knn_mean_ln<<<N, b256, 0, stream>>>(cat, tki, ln_g, ln_b, N);
  // out = [final, sim] @ lin_w.T + lin_b
  gemm_bt<<<dim3(1,gy,1), b256, 0, stream>>>(cat,512, lin_w,512, lin_b, outp,64,0, N,512,64, 0, 0,0,0,0);
}

// Round 12
// 1255.600 us; speedup vs baseline: 1.2345x; 1.0291x over previous
//
#include <hip/hip_runtime.h>

#define FIN 256
#define KNN 50
#define CAP 192
#define J1  512
#define MAXJC 3208

static __device__ __forceinline__ float lrelu02(float v){ return v > 0.f ? v : 0.2f*v; }
static __device__ __forceinline__ unsigned fkey(float v){
  unsigned u = __float_as_uint(v);
  return (u & 0x80000000u) ? ~u : (u | 0x80000000u);
}

// ---------------- CSR construction ----------------
__global__ __launch_bounds__(256) void k_zero_int(int* p, int n){
  int i = blockIdx.x*256 + threadIdx.x; if (i<n) p[i]=0;
}
__global__ __launch_bounds__(256) void k_count_deg(const int* __restrict__ dstv, int* deg, int E){
  int i = blockIdx.x*256 + threadIdx.x; if (i<E) atomicAdd(&deg[dstv[i]], 1);
}
__global__ __launch_bounds__(256) void k_scan(const int* __restrict__ deg, int* offs, int* cursor, int n){
  __shared__ int buf[256]; __shared__ int carry;
  int t = threadIdx.x;
  if (t==0) carry = 0;
  __syncthreads();
  for (int base=0; base<n; base+=256){
    int v = (base+t<n)? deg[base+t] : 0;
    buf[t]=v; __syncthreads();
    for (int off=1; off<256; off<<=1){
      int add = (t>=off)? buf[t-off] : 0;
      __syncthreads();
      buf[t]+=add; __syncthreads();
    }
    int excl = buf[t]-v+carry;
    if (base+t<n){ offs[base+t]=excl; cursor[base+t]=excl; }
    __syncthreads();
    if (t==0) carry += buf[255];
    __syncthreads();
  }
}
__global__ __launch_bounds__(256) void k_fill_csr(const int* __restrict__ dstv, int* cursor, int* csr, int E){
  int i = blockIdx.x*256 + threadIdx.x;
  if (i<E){ int p=atomicAdd(&cursor[dstv[i]],1); csr[p]=i; }
}
__global__ __launch_bounds__(64) void k_sort_csr_wave(int* csr, const int* __restrict__ offs, const int* __restrict__ deg, int n){
  int node = blockIdx.x; if (node>=n) return;
  int t = threadIdx.x;
  int st = offs[node], d = deg[node];
  __shared__ int buf[256];
  if (d > 256){
    if (t==0){
      for (int a=1;a<d;++a){ int v=csr[st+a]; int b=a-1;
        while (b>=0 && csr[st+b]>v){ csr[st+b+1]=csr[st+b]; --b; }
        csr[st+b+1]=v; }
    }
    return;
  }
  for (int q=t;q<d;q+=64) buf[q]=csr[st+q];
  __syncthreads();
  for (int it=0; it<d; ++it){
    int ph = it & 1;
    for (int pidx=t; 2*pidx+ph+1 < d; pidx+=64){
      int a = 2*pidx+ph;
      int va=buf[a], vb=buf[a+1];
      if (va > vb){ buf[a]=vb; buf[a+1]=va; }
    }
    __syncthreads();
  }
  for (int q=t;q<d;q+=64) csr[st+q]=buf[q];
}

// ---------------- fold attention vectors into weights ----------------
__global__ __launch_bounds__(256) void k_fold(
  const float* __restrict__ W, const float* __restrict__ as8, const float* __restrict__ ad8,
  float* __restrict__ Wf)
{
  int o = blockIdx.x;
  int t = threadIdx.x;
  int h = o & 7;
  const float* av = (o<8) ? (as8 + h*128) : (ad8 + h*128);
  const float* wp = W + (size_t)h*128*256 + t;
  float acc = 0.f;
  #pragma unroll 4
  for (int c=0;c<128;++c) acc += av[c] * wp[(size_t)c*256];
  Wf[o*256+t] = acc;
}

// ---------------- generic fp32 GEMM (64x64 tile), z-batched ----------------
__global__ __launch_bounds__(256) void gemm_bt(
    const float* __restrict__ A, int lda,
    const float* __restrict__ W, int ldw,
    const float* __restrict__ bias,
    float* __restrict__ C, int ldc, int coff,
    int M, int Kdim, int O, int relu,
    int az, int wz, int cz, int bz)
{
  A += (size_t)blockIdx.z * az;
  W += (size_t)blockIdx.z * wz;
  if (bias) bias += (size_t)blockIdx.z * bz;
  coff += blockIdx.z * cz;
  __shared__ float As[32][68];
  __shared__ float Ws[32][68];
  int t  = threadIdx.x;
  int n0 = blockIdx.y * 64;
  int o0 = blockIdx.x * 64;
  int tx = t & 15, ty = t >> 4;
  float acc[4][4] = {};
  int kgrp = t & 7;
  int row  = t >> 3;
  for (int k0 = 0; k0 < Kdim; k0 += 32) {
    #pragma unroll
    for (int p = 0; p < 2; ++p) {
      int r = row + 32*p;
      int n = n0 + r;
      float4 v = make_float4(0.f,0.f,0.f,0.f);
      if (n < M) v = *(const float4*)(A + (size_t)n*lda + k0 + 4*kgrp);
      As[4*kgrp+0][r] = v.x; As[4*kgrp+1][r] = v.y;
      As[4*kgrp+2][r] = v.z; As[4*kgrp+3][r] = v.w;
      int o = o0 + r;
      float4 w = make_float4(0.f,0.f,0.f,0.f);
      if (o < O) w = *(const float4*)(W + (size_t)o*ldw + k0 + 4*kgrp);
      Ws[4*kgrp+0][r] = w.x; Ws[4*kgrp+1][r] = w.y;
      Ws[4*kgrp+2][r] = w.z; Ws[4*kgrp+3][r] = w.w;
    }
    __syncthreads();
    #pragma unroll 8
    for (int kk = 0; kk < 32; ++kk) {
      float4 a = *(const float4*)&As[kk][ty*4];
      float4 w = *(const float4*)&Ws[kk][tx*4];
      float av[4] = {a.x,a.y,a.z,a.w};
      float wv[4] = {w.x,w.y,w.z,w.w};
      #pragma unroll
      for (int i=0;i<4;++i)
        #pragma unroll
        for (int j=0;j<4;++j) acc[i][j] += av[i]*wv[j];
    }
    __syncthreads();
  }
  #pragma unroll
  for (int i=0;i<4;++i) {
    int n = n0 + ty*4 + i;
    if (n >= M) continue;
    #pragma unroll
    for (int j=0;j<4;++j) {
      int o = o0 + tx*4 + j;
      if (o >= O) continue;
      float v = acc[i][j] + (bias ? bias[o] : 0.f);
      if (relu) v = fmaxf(v, 0.f);
      C[(size_t)n*ldc + coff + o] = v;
    }
  }
}

// ---------------- 128x128-tile GEMM, O fixed = 128, z-batched ----------------
__global__ __launch_bounds__(256) void gemm128(
    const float* __restrict__ A, int lda,
    const float* __restrict__ W, int ldw,
    const float* __restrict__ bias,
    float* __restrict__ C, int ldc, int coff,
    int M, int Kdim, int relu,
    int az, int wz, int cz, int bz)
{
  A += (size_t)blockIdx.z * az;
  W += (size_t)blockIdx.z * wz;
  const float* bp = bias + (size_t)blockIdx.z * bz;
  int ccol = coff + blockIdx.z * cz;
  __shared__ float As[32][132];
  __shared__ float Ws[32][132];
  int t = threadIdx.x;
  int n0 = blockIdx.y * 128;
  int kg = t & 7, rb = t >> 3;
  int tx = t & 15, ty = t >> 4;
  float acc[2][2][4][4] = {};
  for (int k0 = 0; k0 < Kdim; k0 += 32) {
    __syncthreads();
    #pragma unroll
    for (int p = 0; p < 4; ++p) {
      int r = rb + 32*p;
      int n = n0 + r;
      float4 v = make_float4(0.f,0.f,0.f,0.f);
      if (n < M) v = *(const float4*)(A + (size_t)n*lda + k0 + 4*kg);
      As[4*kg+0][r]=v.x; As[4*kg+1][r]=v.y; As[4*kg+2][r]=v.z; As[4*kg+3][r]=v.w;
      float4 w = *(const float4*)(W + (size_t)r*ldw + k0 + 4*kg);
      Ws[4*kg+0][r]=w.x; Ws[4*kg+1][r]=w.y; Ws[4*kg+2][r]=w.z; Ws[4*kg+3][r]=w.w;
    }
    __syncthreads();
    #pragma unroll 8
    for (int kk = 0; kk < 32; ++kk) {
      float4 A0 = *(const float4*)&As[kk][ty*4];
      float4 A1 = *(const float4*)&As[kk][64+ty*4];
      float4 B0 = *(const float4*)&Ws[kk][tx*4];
      float4 B1 = *(const float4*)&Ws[kk][64+tx*4];
      float av[2][4] = {{A0.x,A0.y,A0.z,A0.w},{A1.x,A1.y,A1.z,A1.w}};
      float bv[2][4] = {{B0.x,B0.y,B0.z,B0.w},{B1.x,B1.y,B1.z,B1.w}};
      #pragma unroll
      for (int pi=0;pi<2;++pi)
        #pragma unroll
        for (int pj=0;pj<2;++pj)
          #pragma unroll
          for (int i=0;i<4;++i)
            #pragma unroll
            for (int j=0;j<4;++j)
              acc[pi][pj][i][j] += av[pi][i]*bv[pj][j];
    }
  }
  #pragma unroll
  for (int pi=0;pi<2;++pi)
    #pragma unroll
    for (int i=0;i<4;++i) {
      int n = n0 + pi*64 + ty*4 + i;
      if (n >= M) continue;
      #pragma unroll
      for (int pj=0;pj<2;++pj)
        #pragma unroll
        for (int j=0;j<4;++j) {
          int o = pj*64 + tx*4 + j;
          float v = acc[pi][pj][i][j] + bp[o];
          if (relu) v = fmaxf(v, 0.f);
          C[(size_t)n*ldc + ccol + o] = v;
        }
    }
}

// ---------------- h2 GEMM v2: 64(i) x 64(o) tile, grid (2, ceil(M/64)) ---------
// k-major XOR-swizzled float4 LDS; acc[4][4]; single ascending-k chain per (n,o).
__global__ __launch_bounds__(256) void gemm_h2(
    const float* __restrict__ A, const float* __restrict__ W,
    float* __restrict__ C, int M)
{
  __shared__ float4 AiS[32*16];   // 8 KB: 32 k x 16 slots (64 rows)
  __shared__ float4 WjS[32*16];   // 8 KB: 32 k x 16 slots (64 cols)
  float* Aif = (float*)AiS;
  float* Wjf = (float*)WjS;
  int t = threadIdx.x;
  int o0 = blockIdx.x * 64;
  int i0 = blockIdx.y * 64;
  int tx = t & 15, ty = t >> 4;
  int kg = t & 7, rw = t >> 3;
  float acc[4][4] = {};
  for (int h=0; h<32; ++h) {      // 32 chunks of k=32 (K=1024)
    if (h) __syncthreads();
    #pragma unroll
    for (int rr=0; rr<2; ++rr) {
      int r = rw + 32*rr;
      int slot = (r>>2) ^ kg;
      int gi = i0 + r;
      float4 v = (gi<M) ? *(const float4*)(A + (size_t)gi*1024 + h*32 + 4*kg) : make_float4(0,0,0,0);
      Aif[((4*kg+0)*16 + slot)*4 + (r&3)] = v.x;
      Aif[((4*kg+1)*16 + slot)*4 + (r&3)] = v.y;
      Aif[((4*kg+2)*16 + slot)*4 + (r&3)] = v.z;
      Aif[((4*kg+3)*16 + slot)*4 + (r&3)] = v.w;
      float4 w = *(const float4*)(W + (size_t)(o0+r)*1024 + h*32 + 4*kg);
      Wjf[((4*kg+0)*16 + slot)*4 + (r&3)] = w.x;
      Wjf[((4*kg+1)*16 + slot)*4 + (r&3)] = w.y;
      Wjf[((4*kg+2)*16 + slot)*4 + (r&3)] = w.z;
      Wjf[((4*kg+3)*16 + slot)*4 + (r&3)] = w.w;
    }
    __syncthreads();
    #pragma unroll 8
    for (int k=0; k<32; ++k) {
      int kc3 = (k>>2)&7;
      float4 A0 = AiS[k*16 + (ty ^ kc3)];
      float4 B0 = WjS[k*16 + (tx ^ kc3)];
      float av[4] = {A0.x,A0.y,A0.z,A0.w};
      float bv[4] = {B0.x,B0.y,B0.z,B0.w};
      #pragma unroll
      for (int i=0;i<4;++i)
        #pragma unroll
        for (int j=0;j<4;++j)
          acc[i][j] += av[i]*bv[j];
    }
  }
  #pragma unroll
  for (int i=0;i<4;++i){
    int n = i0 + ty*4 + i;
    if (n >= M) continue;
    float4 v4 = make_float4(acc[i][0], acc[i][1], acc[i][2], acc[i][3]);
    *(float4*)(C + (size_t)n*128 + o0 + tx*4) = v4;
  }
}

// ---------------- attention logits (gat2, H=1) ----------------
__global__ __launch_bounds__(256) void att_logits(
    const float* __restrict__ hbuf, const float* __restrict__ asrc,
    const float* __restrict__ adst, float* __restrict__ als, float* __restrict__ ald,
    int H, int M)
{
  int gidx = blockIdx.x*256 + threadIdx.x;
  if (gidx >= M*H) return;
  int n = gidx / H, h = gidx % H;
  const float* hp = hbuf + (size_t)n*H*128 + (size_t)h*128;
  const float* as = asrc + h*128;
  const float* ad = adst + h*128;
  float s1=0.f, s2=0.f;
  for (int c=0;c<128;++c){ float v=hp[c]; s1 += v*as[c]; s2 += v*ad[c]; }
  als[gidx]=s1; ald[gidx]=s2;
}

// ---------------- gat1: input-space softmax aggregation ----------------
template<int NH>
__global__ __launch_bounds__(256) void gat1_agg_x(
    const float* __restrict__ x, const float* __restrict__ al1,
    const int* __restrict__ csr, const int* __restrict__ offs, const int* __restrict__ deg,
    const int* __restrict__ srcv,
    float* __restrict__ agg, int h0, int M)
{
  const int n = blockIdx.x, t = threadIdx.x;
  const int d = deg[n], st = offs[n];
  const int lane = t & 63, w = t >> 6;
  __shared__ float sh_ald[NH];
  __shared__ float wpart[4*NH];
  __shared__ float emax_s[NH], den_s[NH];
  __shared__ int   s_lds[128];
  __shared__ float alpha_lds[128*NH];
  if (t < NH) sh_ald[t] = al1[(size_t)n*16 + 8 + h0 + t];
  __syncthreads();
  float lm[NH];
  #pragma unroll
  for (int h=0;h<NH;++h) lm[h] = -__builtin_inff();
  for (int q=t; q<d; q+=256) {
    int s = srcv[csr[st+q]];
    float av[NH];
    float4 a0 = *(const float4*)(al1 + (size_t)s*16 + h0);
    av[0]=a0.x; av[1]=a0.y; av[2]=a0.z; av[3]=a0.w;
    if constexpr (NH==8){
      float4 a1 = *(const float4*)(al1 + (size_t)s*16 + h0 + 4);
      av[4]=a1.x; av[5]=a1.y; av[6]=a1.z; av[7]=a1.w;
    }
    #pragma unroll
    for (int h=0;h<NH;++h) lm[h] = fmaxf(lm[h], lrelu02(av[h] + sh_ald[h]));
  }
  #pragma unroll
  for (int h=0;h<NH;++h){
    float v = lm[h];
    for (int off=32;off>0;off>>=1) v = fmaxf(v, __shfl_down(v, off, 64));
    if (lane==0) wpart[w*NH+h] = v;
  }
  __syncthreads();
  if (t < NH)
    emax_s[t] = fmaxf(fmaxf(wpart[t], wpart[NH+t]), fmaxf(wpart[2*NH+t], wpart[3*NH+t]));
  __syncthreads();
  float ls[NH];
  #pragma unroll
  for (int h=0;h<NH;++h) ls[h]=0.f;
  for (int q=t; q<d; q+=256) {
    int s = srcv[csr[st+q]];
    float av[NH];
    float4 a0 = *(const float4*)(al1 + (size_t)s*16 + h0);
    av[0]=a0.x; av[1]=a0.y; av[2]=a0.z; av[3]=a0.w;
    if constexpr (NH==8){
      float4 a1 = *(const float4*)(al1 + (size_t)s*16 + h0 + 4);
      av[4]=a1.x; av[5]=a1.y; av[6]=a1.z; av[7]=a1.w;
    }
    #pragma unroll
    for (int h=0;h<NH;++h) ls[h] += expf(lrelu02(av[h] + sh_ald[h]) - emax_s[h]);
  }
  #pragma unroll
  for (int h=0;h<NH;++h){
    float v = ls[h];
    for (int off=32;off>0;off>>=1) v += __shfl_down(v, off, 64);
    if (lane==0) wpart[w*NH+h] = v;
  }
  __syncthreads();
  if (t < NH)
    den_s[t] = wpart[t] + wpart[NH+t] + wpart[2*NH+t] + wpart[3*NH+t] + 1e-16f;
  float acc[NH];
  #pragma unroll
  for (int h=0;h<NH;++h) acc[h]=0.f;
  for (int c0=0; c0<d; c0+=128) {
    int cl = min(128, d-c0);
    __syncthreads();
    for (int q=t; q<cl; q+=256) s_lds[q] = srcv[csr[st+c0+q]];
    __syncthreads();
    for (int idx=t; idx<cl*NH; idx+=256) {
      int q = idx / NH, h = idx % NH;
      float als = al1[(size_t)s_lds[q]*16 + h0 + h];
      float v = lrelu02(als + sh_ald[h]);
      alpha_lds[q*NH+h] = expf(v - emax_s[h]) / den_s[h];
    }
    __syncthreads();
    for (int q=0; q<cl; ++q) {
      float xv = x[(size_t)s_lds[q]*FIN + t];
      #pragma unroll
      for (int h=0;h<NH;++h) acc[h] += alpha_lds[q*NH+h] * xv;
    }
  }
  #pragma unroll
  for (int h=0;h<NH;++h) agg[(size_t)n*(NH*256) + h*256 + t] = acc[h];
}

// ---------------- gat2 aggregation: one wave per node ----------------
__global__ __launch_bounds__(256) void gat2_agg_wave(
  const float* __restrict__ h2, const float* __restrict__ als, const float* __restrict__ ald,
  const int* __restrict__ csr, const int* __restrict__ offs, const int* __restrict__ deg,
  const int* __restrict__ srcv, const float* __restrict__ bias,
  float* __restrict__ cat, int M)
{
  int wid = blockIdx.x*4 + (threadIdx.x>>6);
  int lane = threadIdx.x & 63;
  if (wid >= M) return;
  int d = deg[wid], st = offs[wid];
  float aldn = ald[wid];
  float lm = -__builtin_inff();
  for (int q=lane;q<d;q+=64){ int s=srcv[csr[st+q]]; lm = fmaxf(lm, lrelu02(als[s]+aldn)); }
  #pragma unroll
  for (int m=1;m<64;m<<=1) lm = fmaxf(lm, __shfl_xor(lm, m, 64));
  float ls = 0.f;
  for (int q=lane;q<d;q+=64){ int s=srcv[csr[st+q]]; ls += expf(lrelu02(als[s]+aldn)-lm); }
  #pragma unroll
  for (int m=1;m<64;m<<=1) ls += __shfl_xor(ls, m, 64);
  float den = ls + 1e-16f;
  float a0=0.f, a1=0.f;
  for (int q=0;q<d;++q){
    int s = srcv[csr[st+q]];
    float alpha = expf(lrelu02(als[s]+aldn)-lm)/den;
    float2 hv = *(const float2*)(h2 + (size_t)s*128 + lane*2);
    a0 += alpha*hv.x; a1 += alpha*hv.y;
  }
  a0 += bias[lane*2]; a1 += bias[lane*2+1];
  *(float2*)(cat + (size_t)wid*512 + 128 + lane*2) = make_float2(a0,a1);
}

// ---------------- knn: sq norms / init ----------------
__global__ __launch_bounds__(256) void k_sq(const float* __restrict__ g, float* sq, int n){
  int i = blockIdx.x*256+threadIdx.x;
  if (i<n){ const float* p=g+(size_t)i*64; float s=0.f; for(int c=0;c<64;++c) s+=p[c]*p[c]; sq[i]=s; }
}
__global__ __launch_bounds__(256) void k_init_topk(unsigned int* tk, int* ti, int n){
  int i = blockIdx.x*256+threadIdx.x;
  if (i<n){ tk[i]=0u; ti[i]=0x7fffffff; }
}

// ---------------- gram: 64(i) x 128(j) tile, 32 acc, swizzled LDS --------------
// Compile-time slab width JC (static guards -> stable codegen, no spill).
// MODE 0: store slab (row stride J1). MODE 1: threshold filter only.
template<int MODE, int JC>
__global__ __launch_bounds__(256) void gram_k(
    const float* __restrict__ G, const float* __restrict__ sqv,
    const unsigned* __restrict__ kth,
    float* __restrict__ slab, int* __restrict__ cnt,
    unsigned* __restrict__ ck, int* __restrict__ ci,
    int j0, int M)
{
  __shared__ float4 GiS[32*16];
  __shared__ float4 GjS[32*32];
  float* Gif = (float*)GiS;
  float* Gjf = (float*)GjS;
  int t = threadIdx.x;
  int i0  = blockIdx.y * 64;
  int jt0 = blockIdx.x * 128;
  int tx = t & 15, ty = t >> 4;
  int kg = t & 7, rw = t >> 3;
  float acc[2][4][4] = {};
  #pragma unroll
  for (int h=0; h<2; ++h) {
    if (h) __syncthreads();
    #pragma unroll
    for (int rr=0; rr<2; ++rr) {
      int r = rw + 32*rr;
      int slotA = (r>>2) ^ kg;
      int gi = i0 + r;
      float4 v = (gi<M) ? *(const float4*)(G + (size_t)gi*64 + h*32 + 4*kg) : make_float4(0,0,0,0);
      Gif[((4*kg+0)*16 + slotA)*4 + (r&3)] = v.x;
      Gif[((4*kg+1)*16 + slotA)*4 + (r&3)] = v.y;
      Gif[((4*kg+2)*16 + slotA)*4 + (r&3)] = v.z;
      Gif[((4*kg+3)*16 + slotA)*4 + (r&3)] = v.w;
    }
    #pragma unroll
    for (int rr=0; rr<4; ++rr) {
      int r = rw + 32*rr;
      int slotB = (r>>2) ^ kg;
      int gj = j0 + jt0 + r;
      float4 w = (gj<M) ? *(const float4*)(G + (size_t)gj*64 + h*32 + 4*kg) : make_float4(0,0,0,0);
      Gjf[((4*kg+0)*32 + slotB)*4 + (r&3)] = w.x;
      Gjf[((4*kg+1)*32 + slotB)*4 + (r&3)] = w.y;
      Gjf[((4*kg+2)*32 + slotB)*4 + (r&3)] = w.z;
      Gjf[((4*kg+3)*32 + slotB)*4 + (r&3)] = w.w;
    }
    __syncthreads();
    #pragma unroll 8
    for (int k=0; k<32; ++k) {
      int kc3 = (k>>2)&7;
      float4 A0 = GiS[k*16 + (ty ^ kc3)];
      float4 B0 = GjS[k*32 + (tx ^ kc3)];
      float4 B1 = GjS[k*32 + 16 + (tx ^ kc3)];
      float av[4] = {A0.x,A0.y,A0.z,A0.w};
      float bv[2][4] = {{B0.x,B0.y,B0.z,B0.w},{B1.x,B1.y,B1.z,B1.w}};
      #pragma unroll
      for (int pj=0;pj<2;++pj)
        #pragma unroll
        for (int i=0;i<4;++i)
          #pragma unroll
          for (int j=0;j<4;++j)
            acc[pj][i][j] += av[i]*bv[pj][j];
    }
  }
  #pragma unroll
  for (int i=0;i<4;++i){
    int ii = i0 + ty*4 + i;
    if (ii >= M) continue;
    float sqi = sqv[ii];
    #pragma unroll
    for (int pj=0;pj<2;++pj){
      int jl0 = jt0 + pj*64 + tx*4;
      if (jl0 >= JC) continue;            // compile-time slab width
      float4 v4;
      v4.x = 2.f*acc[pj][i][0] - sqi - sqv[j0+jl0+0];
      v4.y = 2.f*acc[pj][i][1] - sqi - sqv[j0+jl0+1];
      v4.z = 2.f*acc[pj][i][2] - sqi - sqv[j0+jl0+2];
      v4.w = 2.f*acc[pj][i][3] - sqi - sqv[j0+jl0+3];
      if (MODE == 0) {
        *(float4*)(slab + (size_t)ii*J1 + jl0) = v4;
      } else {
        unsigned kt = kth[ii];
        float vv[4] = {v4.x, v4.y, v4.z, v4.w};
        #pragma unroll
        for (int j=0;j<4;++j){
          unsigned key = fkey(vv[j]);
          if (key > kt){
            int pos = atomicAdd(&cnt[ii], 1);
            if (pos < CAP){ ck[(size_t)ii*CAP+pos] = key; ci[(size_t)ii*CAP+pos] = j0+jl0+j; }
          }
        }
      }
    }
  }
}

// ---------------- slab-1 top-50: radix select (J1 cols, 4-wave private hist) ---
__global__ __launch_bounds__(256) void topk_radix(
    const float* __restrict__ slab, int j0, int jcount,
    unsigned* __restrict__ tkk, int* __restrict__ tki, unsigned* __restrict__ kth, int M)
{
  __shared__ unsigned keys[J1 + KNN];
  __shared__ int hist[4*256];
  __shared__ int red2[256];
  __shared__ int oldidx[KNN];
  __shared__ int outidx[KNN];
  __shared__ unsigned outkey[KNN];
  __shared__ int b_star, cnt2;
  int i = blockIdx.x, t = threadIdx.x, w = t >> 6;
  for (int p=t; p<jcount; p+=256) keys[p] = fkey(slab[(size_t)i*J1 + p]);
  if (t < KNN){ keys[jcount+t] = tkk[(size_t)i*KNN+t]; oldidx[t] = tki[(size_t)i*KNN+t]; }
  if (t == 0) cnt2 = 0;
  __syncthreads();
  const int total = jcount + KNN;
  unsigned prefix = 0, pmask = 0;
  int need = KNN;
  #pragma unroll
  for (int pass=0; pass<4; ++pass) {
    int shift = 24 - 8*pass;
    hist[t]=0; hist[256+t]=0; hist[512+t]=0; hist[768+t]=0;
    __syncthreads();
    for (int p=t; p<total; p+=256) {
      unsigned k = keys[p];
      if ((k & pmask) == prefix) atomicAdd(&hist[(w<<8) + ((k>>shift)&255)], 1);
    }
    __syncthreads();
    red2[t] = hist[t] + hist[256+t] + hist[512+t] + hist[768+t];
    __syncthreads();
    for (int off=1; off<256; off<<=1) {
      int v = (t+off<256) ? red2[t+off] : 0;
      __syncthreads();
      red2[t] += v;
      __syncthreads();
    }
    if (red2[t] >= need && (t==255 || red2[t+1] < need)) b_star = t;
    __syncthreads();
    int b = b_star;
    need -= (b < 255) ? red2[b+1] : 0;
    prefix |= ((unsigned)b) << shift;
    pmask  |= 0xFFu << shift;
    __syncthreads();
  }
  for (int p=t; p<total; p+=256) {
    unsigned k = keys[p];
    if (k > prefix) {
      int pos = atomicAdd(&cnt2, 1);
      outidx[pos] = (p < jcount) ? (j0 + p) : oldidx[p-jcount];
      outkey[pos] = k;
    }
  }
  __syncthreads();
  int base = cnt2;
  int last = -1;
  for (int it=0; it<need; ++it) {
    int best = 0x7fffffff;
    for (int p=t; p<total; p+=256) {
      if (keys[p] == prefix) {
        int idx = (p < jcount) ? (j0 + p) : oldidx[p-jcount];
        if (idx > last && idx < best) best = idx;
      }
    }
    red2[t] = best; __syncthreads();
    for (int s=128;s>0;s>>=1){ if (t<s) red2[t] = min(red2[t], red2[t+s]); __syncthreads(); }
    if (t==0) { outidx[base+it] = red2[0]; outkey[base+it] = prefix; }
    last = red2[0];
    __syncthreads();
  }
  if (t < KNN){ tkk[(size_t)i*KNN+t] = outkey[t]; tki[(size_t)i*KNN+t] = outidx[t]; }
  if (t == 0) kth[i] = prefix;
}

// ---------------- filter slabs: bitonic fast path; overflow -> recompute+radix --
__global__ __launch_bounds__(256) void topk_fast(
    const float* __restrict__ G, const float* __restrict__ sqv,
    int j0, int jcount,
    const unsigned* __restrict__ ck, const int* __restrict__ ci, const int* __restrict__ cnt,
    unsigned* __restrict__ tkk, int* __restrict__ tki, unsigned* __restrict__ kth, int M)
{
  int i = blockIdx.x, t = threadIdx.x;
  int c = cnt[i];
  if (c <= CAP) {
    __shared__ unsigned skey[256];
    __shared__ int sidx[256];
    unsigned k = 0u; int id = 0x7fffffff;
    if (t < KNN){ k = tkk[(size_t)i*KNN+t]; id = tki[(size_t)i*KNN+t]; }
    else if (t-KNN < c){ k = ck[(size_t)i*CAP + (t-KNN)]; id = ci[(size_t)i*CAP + (t-KNN)]; }
    skey[t] = k; sidx[t] = id;
    for (int size=2; size<=256; size<<=1){
      for (int stride=size>>1; stride>0; stride>>=1){
        __syncthreads();
        int p = t ^ stride;
        if (p > t){
          unsigned k1=skey[t], k2=skey[p]; int i1=sidx[t], i2=sidx[p];
          bool b21 = (k2>k1) || (k2==k1 && i2<i1);
          bool b12 = (k1>k2) || (k1==k2 && i1<i2);
          bool desc = ((t & size) == 0);
          if (desc ? b21 : b12){
            skey[t]=k2; skey[p]=k1; sidx[t]=i2; sidx[p]=i1;
          }
        }
      }
    }
    __syncthreads();
    if (t < KNN){ tkk[(size_t)i*KNN+t] = skey[t]; tki[(size_t)i*KNN+t] = sidx[t]; }
    if (t == 0) kth[i] = skey[KNN-1];
  } else {
    // overflow: recompute row distances (same FMA order as gram) then radix
    __shared__ float gvec[64];
    __shared__ unsigned keys[MAXJC + KNN];
    __shared__ int hist[256];
    __shared__ int red2[256];
    __shared__ int oldidx[KNN];
    __shared__ int outidx[KNN];
    __shared__ unsigned outkey[KNN];
    __shared__ int b_star, cnt2;
    if (t < 64) gvec[t] = G[(size_t)i*64 + t];
    if (t == 0) cnt2 = 0;
    __syncthreads();
    float sqi = sqv[i];
    for (int p=t; p<jcount; p+=256){
      const float4* gj4 = (const float4*)(G + (size_t)(j0+p)*64);
      float acc = 0.f;
      #pragma unroll 4
      for (int q=0;q<16;++q){
        float4 w = gj4[q];
        acc += gvec[4*q+0]*w.x;
        acc += gvec[4*q+1]*w.y;
        acc += gvec[4*q+2]*w.z;
        acc += gvec[4*q+3]*w.w;
      }
      keys[p] = fkey(2.f*acc - sqi - sqv[j0+p]);
    }
    if (t < KNN){ keys[jcount+t] = tkk[(size_t)i*KNN+t]; oldidx[t] = tki[(size_t)i*KNN+t]; }
    __syncthreads();
    const int total = jcount + KNN;
    unsigned prefix = 0, pmask = 0;
    int need = KNN;
    #pragma unroll
    for (int pass=0; pass<4; ++pass) {
      int shift = 24 - 8*pass;
      hist[t] = 0; __syncthreads();
      for (int p=t; p<total; p+=256) {
        unsigned k = keys[p];
        if ((k & pmask) == prefix) atomicAdd(&hist[(k>>shift)&255], 1);
      }
      __syncthreads();
      for (int off=1; off<256; off<<=1) {
        int v = (t+off<256) ? hist[t+off] : 0;
        __syncthreads();
        hist[t] += v;
        __syncthreads();
      }
      if (hist[t] >= need && (t==255 || hist[t+1] < need)) b_star = t;
      __syncthreads();
      int b = b_star;
      need -= (b < 255) ? hist[b+1] : 0;
      prefix |= ((unsigned)b) << shift;
      pmask  |= 0xFFu << shift;
      __syncthreads();
    }
    for (int p=t; p<total; p+=256) {
      unsigned k = keys[p];
      if (k > prefix) {
        int pos = atomicAdd(&cnt2, 1);
        outidx[pos] = (p < jcount) ? (j0 + p) : oldidx[p-jcount];
        outkey[pos] = k;
      }
    }
    __syncthreads();
    int base = cnt2;
    int last = -1;
    for (int it=0; it<need; ++it) {
      int best = 0x7fffffff;
      for (int p=t; p<total; p+=256) {
        if (keys[p] == prefix) {
          int idx = (p < jcount) ? (j0 + p) : oldidx[p-jcount];
          if (idx > last && idx < best) best = idx;
        }
      }
      red2[t] = best; __syncthreads();
      for (int s=128;s>0;s>>=1){ if (t<s) red2[t] = min(red2[t], red2[t+s]); __syncthreads(); }
      if (t==0) { outidx[base+it] = red2[0]; outkey[base+it] = prefix; }
      last = red2[0];
      __syncthreads();
    }
    if (t < KNN){ tkk[(size_t)i*KNN+t] = outkey[t]; tki[(size_t)i*KNN+t] = outidx[t]; }
    if (t == 0) kth[i] = prefix;
  }
}

// ---------------- gather-mean over top-50 + LayerNorm ----------------
__global__ __launch_bounds__(256) void knn_mean_ln(
    float* __restrict__ cat, const int* __restrict__ topi,
    const float* __restrict__ g, const float* __restrict__ b, int M)
{
  int i = blockIdx.x; int t = threadIdx.x;
  __shared__ int idx[KNN];
  __shared__ float red[256];
  if (t<KNN) idx[t]=topi[(size_t)i*KNN+t];
  __syncthreads();
  float acc=0.f;
  for (int r=0;r<KNN;++r) acc += cat[(size_t)idx[r]*512 + t];
  float xval = acc * (1.f/KNN);
  red[t]=xval; __syncthreads();
  for (int s=128;s>0;s>>=1){ if(t<s) red[t]+=red[t+s]; __syncthreads(); }
  float mu = red[0]*(1.f/256.f); __syncthreads();
  float d = xval-mu;
  red[t]=d*d; __syncthreads();
  for (int s=128;s>0;s>>=1){ if(t<s) red[t]+=red[t+s]; __syncthreads(); }
  float var = red[0]*(1.f/256.f);
  float y = d * rsqrtf(var+1e-5f) * g[t] + b[t];
  cat[(size_t)i*512 + 256 + t] = y;
}

// ================================================================
extern "C" void kernel_launch(void* const* d_in, const int* in_sizes, int n_in,
                              void* d_out, int out_size, void* d_ws, size_t ws_size,
                              hipStream_t stream)
{
  const float* x      = (const float*)d_in[0];
  const int*   ei     = (const int*)  d_in[1];
  const float* lin1_w = (const float*)d_in[2];
  const float* lin1_b = (const float*)d_in[3];
  const float* gat1_w = (const float*)d_in[4];
  const float* g1_as  = (const float*)d_in[5];
  const float* g1_ad  = (const float*)d_in[6];
  const float* gat1_b = (const float*)d_in[7];
  const float* gat2_w = (const float*)d_in[8];
  const float* g2_as  = (const float*)d_in[9];
  const float* g2_ad  = (const float*)d_in[10];
  const float* gat2_b = (const float*)d_in[11];
  const float* proj_w = (const float*)d_in[12];
  const float* proj_b = (const float*)d_in[13];
  const float* ln_g   = (const float*)d_in[14];
  const float* ln_b   = (const float*)d_in[15];
  const float* lin_w  = (const float*)d_in[16];
  const float* lin_b  = (const float*)d_in[17];
  float* outp = (float*)d_out;

  const int N = in_sizes[0]/FIN;    // 10000
  const int E = in_sizes[1]/2;      // 320000
  const int* srcv = ei;
  const int* dstv = ei + E;

  size_t needFull = sizeof(float)*((size_t)N*(2048+1024+512+16+128+1+1+64+1+KNN+KNN+1+1+1+1+1+2*CAP) + E + 4096);
  bool full = ws_size >= needFull;
  size_t aggF = full ? (size_t)N*2048 : (size_t)N*1024;

  float* ws = (float*)d_ws;
  size_t f = 0;
  float* agg  = ws + f; f += aggF;
  float* xg   = ws + f; f += (size_t)N*1024;
  float* slab = agg;                      // overlays agg (row stride J1); dead by knn time
  float* cat  = ws + f; f += (size_t)N*512;
  float* al1  = ws + f; f += (size_t)N*16;
  float* h2   = ws + f; f += (size_t)N*128;
  float* al2s = ws + f; f += (size_t)N;
  float* al2d = ws + f; f += (size_t)N;
  float* gsc  = ws + f; f += (size_t)N*64;
  float* sqv  = ws + f; f += (size_t)N;
  unsigned* tkk = (unsigned*)(ws + f); f += (size_t)N*KNN;
  int* tki    = (int*)(ws + f); f += (size_t)N*KNN;
  int* deg    = (int*)(ws + f); f += (size_t)N;
  int* offs   = (int*)(ws + f); f += (size_t)N;
  int* cursor = (int*)(ws + f); f += (size_t)N;
  unsigned* kth = (unsigned*)(ws + f); f += (size_t)N;
  int* ccnt   = (int*)(ws + f); f += (size_t)N;
  unsigned* ck = (unsigned*)(ws + f); f += (size_t)N*CAP;
  int* ci     = (int*)(ws + f); f += (size_t)N*CAP;
  int* csr    = (int*)(ws + f); f += (size_t)E;
  float* Wf   = ws + f; f += 4096;
  (void)n_in; (void)out_size;

  dim3 b256(256);
  int gy = (N+63)/64;
  int gy128 = (N+127)/128;
  int gy64 = (N+63)/64;

  // CSR by dst
  k_zero_int<<<(N+255)/256, b256, 0, stream>>>(deg, N);
  k_count_deg<<<(E+255)/256, b256, 0, stream>>>(dstv, deg, E);
  k_scan<<<1, b256, 0, stream>>>(deg, offs, cursor, N);
  k_fill_csr<<<(E+255)/256, b256, 0, stream>>>(dstv, cursor, csr, E);
  k_sort_csr_wave<<<N, dim3(64), 0, stream>>>(csr, offs, deg, N);

  // fold att vectors into weights; al1 = x @ Wf^T  ([N,16])
  k_fold<<<16, b256, 0, stream>>>(gat1_w, g1_as, g1_ad, Wf);
  gemm_bt<<<dim3(1,gy,1), b256, 0, stream>>>(x,FIN, Wf,FIN, nullptr, al1,16,0, N,FIN,16, 0, 0,0,0,0);

  // x1 = relu(x@lin1_w.T + b) -> cat[:, :128]
  gemm_bt<<<dim3(2,gy,1), b256, 0, stream>>>(x,FIN, lin1_w,FIN, lin1_b, cat,512,0, N,FIN,128, 1, 0,0,0,0);

  // gat1: input-space aggregation, then per-head 128-tile GEMM -> xg = relu(. + b)
  if (full) {
    gat1_agg_x<8><<<N, b256, 0, stream>>>(x, al1, csr, offs, deg, srcv, agg, 0, N);
    gemm128<<<dim3(1,gy128,8), b256, 0, stream>>>(agg,2048, gat1_w,FIN, gat1_b, xg,1024,0,
                                                  N,FIN, 1, 256, 128*256, 128, 128);
  } else {
    for (int h0=0; h0<8; h0+=4) {
      gat1_agg_x<4><<<N, b256, 0, stream>>>(x, al1, csr, offs, deg, srcv, agg, h0, N);
      gemm128<<<dim3(1,gy128,4), b256, 0, stream>>>(agg,1024, gat1_w + (size_t)h0*128*256,FIN,
                                                    gat1_b + h0*128, xg,1024, h0*128,
                                                    N,FIN, 1, 256, 128*256, 128, 128);
    }
  }

  // gat2 (H=1): h2 = xg @ gat2_w.T (64x64 grid (2,157)); logits; wave agg
  gemm_h2<<<dim3(2, gy64), b256, 0, stream>>>(xg, gat2_w, h2, N);
  att_logits<<<(N+255)/256, b256, 0, stream>>>(h2, g2_as, g2_ad, al2s, al2d, 1, N);
  gat2_agg_wave<<<(N+3)/4, b256, 0, stream>>>(h2, al2s, al2d, csr, offs, deg, srcv, gat2_b, cat, N);

  // g_score = final @ proj_w.T + proj_b
  gemm_bt<<<dim3(1,gy,1), b256, 0, stream>>>(cat,512, proj_w,256, proj_b, gsc,64,0, N,256,64, 0, 0,0,0,0);
  k_sq<<<(N+255)/256, b256, 0, stream>>>(gsc, sqv, N);
  k_init_topk<<<(N*KNN+255)/256, b256, 0, stream>>>(tkk, tki, N*KNN);
  k_zero_int<<<(N+255)/256, b256, 0, stream>>>((int*)kth, N);

  // knn with geometric slabs: slab 1 (512) = materialize + radix;
  // slabs 2-5 = threshold filter + bitonic (overflow -> recompute+radix)
  const int sj0[5] = {0, 512, 1536, 3584, 6792};
  const int sjc[5] = {512, 1024, 2048, 3208, 3208};
  for (int s = 0; s < 5; ++s){
    int j0 = sj0[s];
    int jc = sjc[s];
    if (jc > N - j0) jc = N - j0;
    if (jc <= 0) break;
    if (s == 0) {
      gram_k<0,512><<<dim3((512+127)/128, gy64), b256, 0, stream>>>(gsc, sqv, kth, slab, ccnt, ck, ci, j0, N);
      topk_radix<<<N, b256, 0, stream>>>(slab, j0, jc, tkk, tki, kth, N);
    } else {
      k_zero_int<<<(N+255)/256, b256, 0, stream>>>(ccnt, N);
      if (s == 1)
        gram_k<1,1024><<<dim3((1024+127)/128, gy64), b256, 0, stream>>>(gsc, sqv, kth, slab, ccnt, ck, ci, j0, N);
      else if (s == 2)
        gram_k<1,2048><<<dim3((2048+127)/128, gy64), b256, 0, stream>>>(gsc, sqv, kth, slab, ccnt, ck, ci, j0, N);
      else
        gram_k<1,3208><<<dim3((3208+127)/128, gy64), b256, 0, stream>>>(gsc, sqv, kth, slab, ccnt, ck, ci, j0, N);
      topk_fast<<<N, b256, 0, stream>>>(gsc, sqv, j0, jc, ck, ci, ccnt, tkk, tki, kth, N);
    }
  }
  knn_mean_ln<<<N, b256, 0, stream>>>(cat, tki, ln_g, ln_b, N);
  // out = [final, sim] @ lin_w.T + lin_b
  gemm_bt<<<dim3(1,gy,1), b256, 0, stream>>>(cat,512, lin_w,512, lin_b, outp,64,0, N,512,64, 0, 0,0,0,0);
}